// Round 1
// baseline (1551.863 us; speedup 1.0000x reference)
//
#include <hip/hip_runtime.h>
#include <math.h>

#define BATCH 32
#define NN 512
#define DD 256
#define NUMK 4

// ---------- helpers ----------
__device__ __forceinline__ float softplusf(float v) { return log1pf(expf(v)); }

__device__ __forceinline__ unsigned enc_key(float v) {
  unsigned u = __float_as_uint(v);
  return (u & 0x80000000u) ? ~u : (u | 0x80000000u);
}
__device__ __forceinline__ float dec_key(unsigned k) {
  return (k & 0x80000000u) ? __uint_as_float(k & 0x7fffffffu) : __uint_as_float(~k);
}

__device__ __forceinline__ void fma4x4(const float (&As)[16][64], const float (&Bs)[16][64],
                                       int ty, int tx, float (&acc)[4][4]) {
#pragma unroll
  for (int k = 0; k < 16; ++k) {
    float4 a4 = *(const float4*)&As[k][ty * 4];
    float4 b4 = *(const float4*)&Bs[k][tx * 4];
    float av[4] = {a4.x, a4.y, a4.z, a4.w};
    float bv[4] = {b4.x, b4.y, b4.z, b4.w};
#pragma unroll
    for (int i = 0; i < 4; ++i)
#pragma unroll
      for (int j = 0; j < 4; ++j)
        acc[i][j] = fmaf(av[i], bv[j], acc[i][j]);
  }
}

// ---------- init ----------
__global__ void k_init(float* log_t, float* log_s, float* z, unsigned* keys) {
  const float c0 = logf(1.0f / NN + 1e-8f) + logf(1.0f / DD + 1e-8f);
  size_t total = (size_t)BATCH * NN * DD;
  for (size_t i = (size_t)blockIdx.x * blockDim.x + threadIdx.x; i < total;
       i += (size_t)gridDim.x * blockDim.x) {
    log_t[i] = c0;
    log_s[i] = c0;
    z[i] = 0.0f;
  }
  if (blockIdx.x == 0 && threadIdx.x == 0) { keys[0] = 0u; keys[1] = 0u; }
}

// ---------- c1 = x^T x / N  (B,D,D) ----------
__global__ __launch_bounds__(256) void k_c1(const float* __restrict__ x, float* __restrict__ c1) {
  int b = blockIdx.z;
  const float* X = x + (size_t)b * NN * DD;
  float* C = c1 + (size_t)b * DD * DD;
  __shared__ float As[16][64], Bs[16][64];
  int row0 = blockIdx.y * 64, col0 = blockIdx.x * 64;
  int tid = threadIdx.y * 16 + threadIdx.x;
  int li = tid & 63, lk0 = tid >> 6;
  float acc[4][4] = {};
  for (int k0 = 0; k0 < NN; k0 += 16) {
#pragma unroll
    for (int s = 0; s < 4; ++s) {
      int kk = lk0 + s * 4;
      As[kk][li] = X[(size_t)(k0 + kk) * DD + row0 + li];
      Bs[kk][li] = X[(size_t)(k0 + kk) * DD + col0 + li];
    }
    __syncthreads();
    fma4x4(As, Bs, threadIdx.y, threadIdx.x, acc);
    __syncthreads();
  }
  const float inv = 1.0f / NN;
#pragma unroll
  for (int i = 0; i < 4; ++i) {
    float4 o = make_float4(acc[i][0] * inv, acc[i][1] * inv, acc[i][2] * inv, acc[i][3] * inv);
    *(float4*)&C[(size_t)(row0 + threadIdx.y * 4 + i) * DD + col0 + threadIdx.x * 4] = o;
  }
}

// ---------- c2 = x x^T / D  (B,N,N) ----------
__global__ __launch_bounds__(256) void k_c2(const float* __restrict__ x, float* __restrict__ c2) {
  int b = blockIdx.z;
  const float* X = x + (size_t)b * NN * DD;
  float* C = c2 + (size_t)b * NN * NN;
  __shared__ float As[16][64], Bs[16][64];
  int row0 = blockIdx.y * 64, col0 = blockIdx.x * 64;
  int tid = threadIdx.y * 16 + threadIdx.x;
  int lk = tid & 15, li0 = tid >> 4;
  float acc[4][4] = {};
  for (int k0 = 0; k0 < DD; k0 += 16) {
#pragma unroll
    for (int s = 0; s < 4; ++s) {
      int i = li0 + s * 16;
      As[lk][i] = X[(size_t)(row0 + i) * DD + k0 + lk];
      Bs[lk][i] = X[(size_t)(col0 + i) * DD + k0 + lk];
    }
    __syncthreads();
    fma4x4(As, Bs, threadIdx.y, threadIdx.x, acc);
    __syncthreads();
  }
  const float inv = 1.0f / DD;
#pragma unroll
  for (int i = 0; i < 4; ++i) {
    float4 o = make_float4(acc[i][0] * inv, acc[i][1] * inv, acc[i][2] * inv, acc[i][3] * inv);
    *(float4*)&C[(size_t)(row0 + threadIdx.y * 4 + i) * NN + col0 + threadIdx.x * 4] = o;
  }
}

// ---------- global max (order-preserving key atomic) ----------
__global__ void k_max(const float* __restrict__ a, size_t n, unsigned* slot) {
  float m = -1e30f;
  for (size_t i = (size_t)blockIdx.x * blockDim.x + threadIdx.x; i < n;
       i += (size_t)gridDim.x * blockDim.x)
    m = fmaxf(m, a[i]);
#pragma unroll
  for (int o = 32; o > 0; o >>= 1) m = fmaxf(m, __shfl_xor(m, o));
  __shared__ float sm[4];
  if ((threadIdx.x & 63) == 0) sm[threadIdx.x >> 6] = m;
  __syncthreads();
  if (threadIdx.x == 0) {
    m = fmaxf(fmaxf(sm[0], sm[1]), fmaxf(sm[2], sm[3]));
    atomicMax(slot, enc_key(m));
  }
}

// ---------- scalar params + constant marginal recurrences ----------
// P[0..3]=a0  P[4..7]=a1_eff  P[8..11]=rho  P[12..15]=mu_used  P[16..19]=eta_used
__global__ void k_params(const float* a0p, const float* a1p, const float* a2p,
                         const float* a3p, const float* rhop, float* P, unsigned* keys) {
  if (threadIdx.x != 0 || blockIdx.x != 0) return;
  float M1 = dec_key(keys[0]);
  float M2 = dec_key(keys[1]);
  float lq0 = logf(1.0f / NN + 1e-8f);
  float lp0 = logf(1.0f / DD + 1e-8f);
  float mu = lq0, eta = lp0, z1 = 0.f, z2 = 0.f;
  for (int k = 0; k < NUMK; ++k) {
    float a0 = softplusf(a0p[k]), a1 = softplusf(a1p[k]);
    float a2 = softplusf(a2p[k]), a3 = softplusf(a3p[k]);
    float rho = softplusf(rhop[k]);
    P[0 + k] = a0;
    P[4 + k] = a1 / (M1 * M2);
    P[8 + k] = rho;
    P[12 + k] = mu;   // log_mu entering iteration k
    P[16 + k] = eta;  // log_eta entering iteration k
    // marginal prox + dual (log_t1 == mu exactly; log_s1 == eta exactly)
    float t1 = mu;
    mu = (a2 * lq0 + rho * t1 - z1) / (a2 + rho);
    z1 += rho * (expf(mu) - expf(t1));
    float s1 = eta;
    eta = (a3 * lp0 + rho * s1 - z2) / (a3 + rho);
    z2 += rho * (expf(eta) - expf(s1));
  }
}

// ---------- U = c2 @ exp(L)  (B,N,D) ----------
__global__ __launch_bounds__(256) void k_gemm_cE(const float* __restrict__ c2,
                                                 const float* __restrict__ L,
                                                 float* __restrict__ U) {
  int b = blockIdx.z;
  const float* A = c2 + (size_t)b * NN * NN;
  const float* Bm = L + (size_t)b * NN * DD;
  float* Cm = U + (size_t)b * NN * DD;
  __shared__ float As[16][64], Bs[16][64];
  int row0 = blockIdx.y * 64, col0 = blockIdx.x * 64;
  int tid = threadIdx.y * 16 + threadIdx.x;
  int lkA = tid & 15, liA = tid >> 4;
  int ljB = tid & 63, lkB0 = tid >> 6;
  float acc[4][4] = {};
  for (int k0 = 0; k0 < NN; k0 += 16) {
#pragma unroll
    for (int s = 0; s < 4; ++s) {
      int i = liA + s * 16;
      As[lkA][i] = A[(size_t)(row0 + i) * NN + k0 + lkA];
      int kk = lkB0 + s * 4;
      Bs[kk][ljB] = expf(Bm[(size_t)(k0 + kk) * DD + col0 + ljB]);
    }
    __syncthreads();
    fma4x4(As, Bs, threadIdx.y, threadIdx.x, acc);
    __syncthreads();
  }
#pragma unroll
  for (int i = 0; i < 4; ++i) {
    float4 o = make_float4(acc[i][0], acc[i][1], acc[i][2], acc[i][3]);
    *(float4*)&Cm[(size_t)(row0 + threadIdx.y * 4 + i) * DD + col0 + threadIdx.x * 4] = o;
  }
}

// ---------- G = epilogue(U @ c1) ----------
// MODE 0: G = (xd + a1e*acc + z + rho*L)/(rho+a0)     (pre T-update y)
// MODE 1: G = (a1e*acc - z + rho*L)/rho               (pre S-update y2)
template <int MODE>
__global__ __launch_bounds__(256) void k_gemm_epi(const float* __restrict__ Uin,
                                                  const float* __restrict__ c1,
                                                  const float* __restrict__ xd,
                                                  const float* __restrict__ zbuf,
                                                  const float* __restrict__ Lbuf,
                                                  float* __restrict__ G,
                                                  const float* __restrict__ P, int kiter) {
  int b = blockIdx.z;
  const float* A = Uin + (size_t)b * NN * DD;
  const float* Bm = c1 + (size_t)b * DD * DD;
  size_t base = (size_t)b * NN * DD;
  __shared__ float As[16][64], Bs[16][64];
  int row0 = blockIdx.y * 64, col0 = blockIdx.x * 64;
  int tid = threadIdx.y * 16 + threadIdx.x;
  int lkA = tid & 15, liA = tid >> 4;
  int ljB = tid & 63, lkB0 = tid >> 6;
  float acc[4][4] = {};
  for (int k0 = 0; k0 < DD; k0 += 16) {
#pragma unroll
    for (int s = 0; s < 4; ++s) {
      int i = liA + s * 16;
      As[lkA][i] = A[(size_t)(row0 + i) * DD + k0 + lkA];
      int kk = lkB0 + s * 4;
      Bs[kk][ljB] = Bm[(size_t)(k0 + kk) * DD + col0 + ljB];
    }
    __syncthreads();
    fma4x4(As, Bs, threadIdx.y, threadIdx.x, acc);
    __syncthreads();
  }
  float a0 = P[0 + kiter], a1e = P[4 + kiter], rho = P[8 + kiter];
#pragma unroll
  for (int i = 0; i < 4; ++i) {
    int r = row0 + threadIdx.y * 4 + i;
    size_t idx = base + (size_t)r * DD + col0 + threadIdx.x * 4;
    float4 zv = *(const float4*)&zbuf[idx];
    float4 lv = *(const float4*)&Lbuf[idx];
    float4 o;
    if (MODE == 0) {
      float4 xv = *(const float4*)&xd[idx];
      float inv = 1.0f / (rho + a0);
      o.x = (xv.x + a1e * acc[i][0] + zv.x + rho * lv.x) * inv;
      o.y = (xv.y + a1e * acc[i][1] + zv.y + rho * lv.y) * inv;
      o.z = (xv.z + a1e * acc[i][2] + zv.z + rho * lv.z) * inv;
      o.w = (xv.w + a1e * acc[i][3] + zv.w + rho * lv.w) * inv;
    } else {
      float inv = 1.0f / rho;
      o.x = (a1e * acc[i][0] - zv.x + rho * lv.x) * inv;
      o.y = (a1e * acc[i][1] - zv.y + rho * lv.y) * inv;
      o.z = (a1e * acc[i][2] - zv.z + rho * lv.z) * inv;
      o.w = (a1e * acc[i][3] - zv.w + rho * lv.w) * inv;
    }
    *(float4*)&G[idx] = o;
  }
}

// ---------- T-update: log_t = mu + log_softmax(G, axis=d) ----------
__global__ __launch_bounds__(256) void k_trow(const float* __restrict__ G,
                                              float* __restrict__ log_t,
                                              const float* __restrict__ P, int kiter) {
  size_t row = blockIdx.x;  // b*N + n
  float y = G[row * DD + threadIdx.x];
  float m = y;
#pragma unroll
  for (int o = 32; o > 0; o >>= 1) m = fmaxf(m, __shfl_xor(m, o));
  __shared__ float sm[4], ss[4];
  int wv = threadIdx.x >> 6;
  if ((threadIdx.x & 63) == 0) sm[wv] = m;
  __syncthreads();
  m = fmaxf(fmaxf(sm[0], sm[1]), fmaxf(sm[2], sm[3]));
  float e = expf(y - m);
  float sum = e;
#pragma unroll
  for (int o = 32; o > 0; o >>= 1) sum += __shfl_xor(sum, o);
  if ((threadIdx.x & 63) == 0) ss[wv] = sum;
  __syncthreads();
  float lse = m + logf(ss[0] + ss[1] + ss[2] + ss[3]);
  log_t[row * DD + threadIdx.x] = P[12 + kiter] + y - lse;
}

// ---------- S-update (axis=n) + fused dual z-update ----------
__global__ __launch_bounds__(256) void k_scol(const float* __restrict__ G,
                                              const float* __restrict__ log_t,
                                              float* __restrict__ log_s,
                                              float* __restrict__ z,
                                              const float* __restrict__ P, int kiter) {
  int b = blockIdx.x >> 2;
  int d0 = (blockIdx.x & 3) << 6;
  int tx = threadIdx.x & 63;
  int ty = threadIdx.x >> 6;
  int d = d0 + tx;
  size_t base = (size_t)b * NN * DD;
  __shared__ float red[4][64];
  float m = -1e30f;
  for (int n = ty; n < NN; n += 4) m = fmaxf(m, G[base + (size_t)n * DD + d]);
  red[ty][tx] = m;
  __syncthreads();
  m = fmaxf(fmaxf(red[0][tx], red[1][tx]), fmaxf(red[2][tx], red[3][tx]));
  __syncthreads();
  float sum = 0.0f;
  for (int n = ty; n < NN; n += 4) sum += expf(G[base + (size_t)n * DD + d] - m);
  red[ty][tx] = sum;
  __syncthreads();
  sum = red[0][tx] + red[1][tx] + red[2][tx] + red[3][tx];
  float lse = m + logf(sum);
  float eta = P[16 + kiter], rho = P[8 + kiter];
  for (int n = ty; n < NN; n += 4) {
    size_t idx = base + (size_t)n * DD + d;
    float ls = eta + G[idx] - lse;
    log_s[idx] = ls;
    z[idx] += rho * (expf(log_t[idx]) - expf(ls));
  }
}

// ---------- out[b,d] = D * sum_n x*exp(log_t) ----------
__global__ __launch_bounds__(256) void k_out(const float* __restrict__ x,
                                             const float* __restrict__ log_t,
                                             float* __restrict__ out) {
  int b = blockIdx.x, d = threadIdx.x;
  const float* X = x + (size_t)b * NN * DD;
  const float* LT = log_t + (size_t)b * NN * DD;
  float acc = 0.0f;
  for (int n = 0; n < NN; ++n) acc += X[(size_t)n * DD + d] * expf(LT[(size_t)n * DD + d]);
  out[(size_t)b * DD + d] = (float)DD * acc;
}

// ---------- launch ----------
extern "C" void kernel_launch(void* const* d_in, const int* in_sizes, int n_in,
                              void* d_out, int out_size, void* d_ws, size_t ws_size,
                              hipStream_t stream) {
  const float* x = (const float*)d_in[0];
  const float* a0p = (const float*)d_in[1];
  const float* a1p = (const float*)d_in[2];
  const float* a2p = (const float*)d_in[3];
  const float* a3p = (const float*)d_in[4];
  const float* rhop = (const float*)d_in[5];
  float* out = (float*)d_out;

  float* ws = (float*)d_ws;
  size_t o = 0;
  float* c1 = ws + o;    o += (size_t)BATCH * DD * DD;
  float* c2 = ws + o;    o += (size_t)BATCH * NN * NN;
  float* log_t = ws + o; o += (size_t)BATCH * NN * DD;
  float* log_s = ws + o; o += (size_t)BATCH * NN * DD;
  float* zb = ws + o;    o += (size_t)BATCH * NN * DD;
  float* Ub = ws + o;    o += (size_t)BATCH * NN * DD;
  float* Gb = ws + o;    o += (size_t)BATCH * NN * DD;
  float* P = ws + o;     // 64 floats
  unsigned* keys = (unsigned*)(P + 20);

  dim3 b16(16, 16);
  k_init<<<2048, 256, 0, stream>>>(log_t, log_s, zb, keys);
  k_c1<<<dim3(4, 4, BATCH), b16, 0, stream>>>(x, c1);
  k_c2<<<dim3(8, 8, BATCH), b16, 0, stream>>>(x, c2);
  k_max<<<1024, 256, 0, stream>>>(c1, (size_t)BATCH * DD * DD, keys + 0);
  k_max<<<2048, 256, 0, stream>>>(c2, (size_t)BATCH * NN * NN, keys + 1);
  k_params<<<1, 1, 0, stream>>>(a0p, a1p, a2p, a3p, rhop, P, keys);

  for (int k = 0; k < NUMK; ++k) {
    k_gemm_cE<<<dim3(4, 8, BATCH), b16, 0, stream>>>(c2, log_s, Ub);
    k_gemm_epi<0><<<dim3(4, 8, BATCH), b16, 0, stream>>>(Ub, c1, x, zb, log_s, Gb, P, k);
    k_trow<<<BATCH * NN, 256, 0, stream>>>(Gb, log_t, P, k);
    k_gemm_cE<<<dim3(4, 8, BATCH), b16, 0, stream>>>(c2, log_t, Ub);
    k_gemm_epi<1><<<dim3(4, 8, BATCH), b16, 0, stream>>>(Ub, c1, x, zb, log_t, Gb, P, k);
    k_scol<<<128, 256, 0, stream>>>(Gb, log_t, log_s, zb, P, k);
  }
  k_out<<<BATCH, 256, 0, stream>>>(x, log_t, out);
}

// Round 2
// 515.183 us; speedup vs baseline: 3.0123x; 3.0123x over previous
//
#include <hip/hip_runtime.h>
#include <math.h>

#define BATCH 32
#define NN 512
#define DD 256
#define NUMK 4

typedef __attribute__((ext_vector_type(8))) short bf16x8;
typedef __attribute__((ext_vector_type(4))) float f32x4;
typedef __attribute__((ext_vector_type(4))) unsigned short u16x4;

__device__ __forceinline__ float softplusf(float v) { return log1pf(expf(v)); }

__device__ __forceinline__ unsigned enc_key(float v) {
  unsigned u = __float_as_uint(v);
  return (u & 0x80000000u) ? ~u : (u | 0x80000000u);
}
__device__ __forceinline__ float dec_key(unsigned k) {
  return (k & 0x80000000u) ? __uint_as_float(k & 0x7fffffffu) : __uint_as_float(~k);
}
__device__ __forceinline__ unsigned short f2b(float f) {
  unsigned u = __float_as_uint(f);
  unsigned r = (u + 0x7fffu + ((u >> 16) & 1u)) >> 16;
  return (unsigned short)r;
}

#define GLDS(gp, lp)                                                   \
  __builtin_amdgcn_global_load_lds(                                    \
      (__attribute__((address_space(1))) void*)(void*)(gp),            \
      (__attribute__((address_space(3))) void*)(lp), 16, 0, 0)

// ---------- prep: xb = bf16(x) [n][d], xTb = bf16(x^T) [d][n]; zero max keys ----------
__global__ __launch_bounds__(256) void k_prep(const float* __restrict__ x,
                                              short* __restrict__ xb,
                                              short* __restrict__ xTb,
                                              unsigned* keys) {
  __shared__ float t[64][65];
  int b = blockIdx.z, n0 = blockIdx.y * 64, d0 = blockIdx.x * 64;
  if (blockIdx.x == 0 && blockIdx.y == 0 && blockIdx.z == 0 && threadIdx.x == 0) {
    keys[0] = 0u; keys[1] = 0u;
  }
  const float* X = x + (size_t)b * NN * DD;
  int col = threadIdx.x & 63, rr = threadIdx.x >> 6;
#pragma unroll
  for (int s = 0; s < 16; ++s) {
    int row = s * 4 + rr;
    float v = X[(size_t)(n0 + row) * DD + d0 + col];
    t[row][col] = v;
    xb[(size_t)b * NN * DD + (size_t)(n0 + row) * DD + d0 + col] = (short)f2b(v);
  }
  __syncthreads();
#pragma unroll
  for (int s = 0; s < 16; ++s) {
    int row = s * 4 + rr;  // d within tile
    xTb[(size_t)b * DD * NN + (size_t)(d0 + row) * NN + n0 + col] = (short)f2b(t[col][row]);
  }
}

// ---------- init ADMM state ----------
__global__ void k_init(float* log_s, short* eS, float* z) {
  const float c0 = logf(1.0f / NN + 1e-8f) + logf(1.0f / DD + 1e-8f);
  const short e0 = (short)f2b(expf(c0));
  size_t total = (size_t)BATCH * NN * DD;
  for (size_t i = (size_t)blockIdx.x * blockDim.x + threadIdx.x; i < total;
       i += (size_t)gridDim.x * blockDim.x) {
    log_s[i] = c0;
    eS[i] = e0;
    z[i] = 0.0f;
  }
}

// ---------- scalar params + constant marginal recurrences ----------
__global__ void k_params(const float* a0p, const float* a1p, const float* a2p,
                         const float* a3p, const float* rhop, float* P, unsigned* keys) {
  if (threadIdx.x != 0 || blockIdx.x != 0) return;
  float M1 = dec_key(keys[0]);  // max c1
  float M2 = dec_key(keys[1]);  // max c2
  float lq0 = logf(1.0f / NN + 1e-8f);
  float lp0 = logf(1.0f / DD + 1e-8f);
  float mu = lq0, eta = lp0, z1 = 0.f, z2 = 0.f;
  for (int k = 0; k < NUMK; ++k) {
    float a0 = softplusf(a0p[k]), a1 = softplusf(a1p[k]);
    float a2 = softplusf(a2p[k]), a3 = softplusf(a3p[k]);
    float rho = softplusf(rhop[k]);
    P[0 + k] = a0;
    P[4 + k] = a1 / (M1 * M2);
    P[8 + k] = rho;
    P[12 + k] = mu;
    P[16 + k] = eta;
    float t1 = mu;
    mu = (a2 * lq0 + rho * t1 - z1) / (a2 + rho);
    z1 += rho * (expf(mu) - expf(t1));
    float s1 = eta;
    eta = (a3 * lp0 + rho * s1 - z2) / (a3 + rho);
    z2 += rho * (expf(eta) - expf(s1));
  }
}

// ---------- unified bf16 MFMA GEMM, 128x128 tile, BK=32, transposed C-store ----------
// C[m][c] = sum_k A[m][k]*B[c][k]; stored transposed: out[c*ldo + m].
// OUTK 0: bf16 out, *scale, fused global atomicMax     (Gram matrices)
// OUTK 1: bf16 out                                     (V = E @ c1 -> V^T)
// OUTK 2: f32 out w/ epi (x + a1e*W + z + rho*L)/(rho+a0)   (y,  pre-T softmax)
// OUTK 3: f32 out w/ epi (a1e*W - z + rho*L)/rho            (y2, pre-S softmax)
template <int K, int OUTK>
__global__ __launch_bounds__(256) void k_mfma(
    const short* __restrict__ A, size_t sA, int lda,
    const short* __restrict__ Bp, size_t sB, int ldb,
    void* __restrict__ outp, size_t sO, int ldo,
    float scale, unsigned* maxslot,
    const float* __restrict__ xg, const float* __restrict__ zg,
    const float* __restrict__ Lg, const float* __restrict__ P, int kiter) {
  __shared__ short As[128 * 32];
  __shared__ short Bs[128 * 32];
  const int b = blockIdx.z;
  const int m0 = blockIdx.y * 128, n0 = blockIdx.x * 128;
  const int tid = threadIdx.x, wave = tid >> 6, lane = tid & 63;
  const int ln = lane & 15, kg = lane >> 4;
  const int wr = (wave >> 1) * 64, wc = (wave & 1) * 64;
  const short* Ab = A + (size_t)b * sA;
  const short* Bb = Bp + (size_t)b * sB;
  const int srow = lane >> 2;        // 0..15 within 16-row chunk
  const int scol = (lane & 3) * 8;   // shorts within row

  f32x4 acc[4][4];
#pragma unroll
  for (int i = 0; i < 4; ++i)
#pragma unroll
    for (int j = 0; j < 4; ++j) acc[i][j] = (f32x4){0.f, 0.f, 0.f, 0.f};

  for (int k0 = 0; k0 < K; k0 += 32) {
    __syncthreads();  // LDS safe to overwrite
#pragma unroll
    for (int s = 0; s < 2; ++s) {
      int c = wave * 2 + s;          // 16-row chunk id, rows c*16..c*16+15
      int row = c * 16 + srow;
      GLDS(Ab + (size_t)(m0 + row) * lda + k0 + scol, &As[c * 512]);
      GLDS(Bb + (size_t)(n0 + row) * ldb + k0 + scol, &Bs[c * 512]);
    }
    __syncthreads();  // drains vmcnt before barrier
    bf16x8 af[4], bfr[4];
#pragma unroll
    for (int i = 0; i < 4; ++i)
      af[i] = *(const bf16x8*)&As[(wr + i * 16 + ln) * 32 + kg * 8];
#pragma unroll
    for (int j = 0; j < 4; ++j)
      bfr[j] = *(const bf16x8*)&Bs[(wc + j * 16 + ln) * 32 + kg * 8];
#pragma unroll
    for (int i = 0; i < 4; ++i)
#pragma unroll
      for (int j = 0; j < 4; ++j)
        acc[i][j] = __builtin_amdgcn_mfma_f32_16x16x32_bf16(af[i], bfr[j], acc[i][j], 0, 0, 0);
  }

  if (OUTK <= 1) {
    unsigned short* ot = (unsigned short*)outp + (size_t)b * sO;
    float tmax = -1e30f;
#pragma unroll
    for (int i = 0; i < 4; ++i) {
      int r = m0 + wr + i * 16 + kg * 4;
#pragma unroll
      for (int j = 0; j < 4; ++j) {
        int c = n0 + wc + j * 16 + ln;
        u16x4 pk;
#pragma unroll
        for (int q = 0; q < 4; ++q) {
          float v = acc[i][j][q] * scale;
          if (OUTK == 0) tmax = fmaxf(tmax, v);
          pk[q] = f2b(v);
        }
        *(u16x4*)&ot[(size_t)c * ldo + r] = pk;
      }
    }
    if (OUTK == 0) {
#pragma unroll
      for (int o = 32; o > 0; o >>= 1) tmax = fmaxf(tmax, __shfl_xor(tmax, o));
      __syncthreads();
      float* smf = (float*)As;
      if (lane == 0) smf[wave] = tmax;
      __syncthreads();
      if (tid == 0)
        atomicMax(maxslot, enc_key(fmaxf(fmaxf(smf[0], smf[1]), fmaxf(smf[2], smf[3]))));
    }
  } else {
    float* G = (float*)outp + (size_t)b * sO;
    const float* xb_ = xg + (size_t)b * sO;
    const float* zb_ = zg + (size_t)b * sO;
    const float* Lb_ = Lg + (size_t)b * sO;
    const float a0 = P[kiter], a1e = P[4 + kiter], rho = P[8 + kiter];
    const float inv = (OUTK == 2) ? 1.0f / (rho + a0) : 1.0f / rho;
#pragma unroll
    for (int i = 0; i < 4; ++i) {
      int r = m0 + wr + i * 16 + kg * 4;  // d index
#pragma unroll
      for (int j = 0; j < 4; ++j) {
        int c = n0 + wc + j * 16 + ln;    // n index
        size_t idx = (size_t)c * DD + r;
        f32x4 zv = *(const f32x4*)&zb_[idx];
        f32x4 lv = *(const f32x4*)&Lb_[idx];
        f32x4 o;
        if (OUTK == 2) {
          f32x4 xv = *(const f32x4*)&xb_[idx];
#pragma unroll
          for (int q = 0; q < 4; ++q)
            o[q] = (xv[q] + a1e * acc[i][j][q] + zv[q] + rho * lv[q]) * inv;
        } else {
#pragma unroll
          for (int q = 0; q < 4; ++q)
            o[q] = (a1e * acc[i][j][q] - zv[q] + rho * lv[q]) * inv;
        }
        *(f32x4*)&G[idx] = o;
      }
    }
  }
}

// ---------- T-update: log_t = mu + log_softmax over d; eT = exp(log_t) bf16 ----------
__global__ __launch_bounds__(256) void k_trow(const float* __restrict__ G,
                                              float* __restrict__ log_t,
                                              short* __restrict__ eT,
                                              const float* __restrict__ P, int kiter) {
  size_t row = blockIdx.x;  // b*N + n
  float y = G[row * DD + threadIdx.x];
  float m = y;
#pragma unroll
  for (int o = 32; o > 0; o >>= 1) m = fmaxf(m, __shfl_xor(m, o));
  __shared__ float sm[4], ss[4];
  int wv = threadIdx.x >> 6;
  if ((threadIdx.x & 63) == 0) sm[wv] = m;
  __syncthreads();
  m = fmaxf(fmaxf(sm[0], sm[1]), fmaxf(sm[2], sm[3]));
  float sum = expf(y - m);
#pragma unroll
  for (int o = 32; o > 0; o >>= 1) sum += __shfl_xor(sum, o);
  if ((threadIdx.x & 63) == 0) ss[wv] = sum;
  __syncthreads();
  float lse = m + logf(ss[0] + ss[1] + ss[2] + ss[3]);
  float lt = P[12 + kiter] + y - lse;
  log_t[row * DD + threadIdx.x] = lt;
  eT[row * DD + threadIdx.x] = (short)f2b(expf(lt));
}

// ---------- S-update over n (online LSE) + eS bf16 + fused dual z-update ----------
__global__ __launch_bounds__(1024) void k_scol(const float* __restrict__ G,
                                               const float* __restrict__ log_t,
                                               float* __restrict__ log_s,
                                               short* __restrict__ eS,
                                               float* __restrict__ z,
                                               const float* __restrict__ P, int kiter) {
  int b = blockIdx.x >> 2;
  int d0 = (blockIdx.x & 3) << 6;
  int tx = threadIdx.x & 63;
  int ty = threadIdx.x >> 6;  // 0..15
  int d = d0 + tx;
  size_t base = (size_t)b * NN * DD;
  __shared__ float red_m[16][64], red_s[16][64], lse_s[64];
  float m = -1e30f, s = 0.0f;
  for (int n = ty; n < NN; n += 16) {
    float g = G[base + (size_t)n * DD + d];
    float nm = fmaxf(m, g);
    s = s * expf(m - nm) + expf(g - nm);
    m = nm;
  }
  red_m[ty][tx] = m;
  red_s[ty][tx] = s;
  __syncthreads();
  if (ty == 0) {
    float M = red_m[0][tx], S = red_s[0][tx];
#pragma unroll
    for (int t = 1; t < 16; ++t) {
      float m2 = red_m[t][tx], s2 = red_s[t][tx];
      float nm = fmaxf(M, m2);
      S = S * expf(M - nm) + s2 * expf(m2 - nm);
      M = nm;
    }
    lse_s[tx] = M + logf(S);
  }
  __syncthreads();
  float lse = lse_s[tx];
  float eta = P[16 + kiter], rho = P[8 + kiter];
  for (int n = ty; n < NN; n += 16) {
    size_t idx = base + (size_t)n * DD + d;
    float ls = eta + G[idx] - lse;
    log_s[idx] = ls;
    float es = expf(ls);
    eS[idx] = (short)f2b(es);
    z[idx] += rho * (expf(log_t[idx]) - es);
  }
}

// ---------- output: out[b,d] = D * sum_n x*exp(log_t) ----------
__global__ __launch_bounds__(256) void k_out1(const float* __restrict__ x,
                                              const float* __restrict__ log_t,
                                              float* __restrict__ part) {
  int bc = blockIdx.x;  // b*8 + chunk
  int b = bc >> 3, ch = bc & 7;
  int d = threadIdx.x;
  size_t base = (size_t)b * NN * DD;
  float acc = 0.0f;
  for (int n = ch * 64; n < ch * 64 + 64; ++n) {
    size_t idx = base + (size_t)n * DD + d;
    acc += x[idx] * expf(log_t[idx]);
  }
  part[(size_t)bc * DD + d] = acc;
}
__global__ __launch_bounds__(256) void k_out2(const float* __restrict__ part,
                                              float* __restrict__ out) {
  int b = blockIdx.x, d = threadIdx.x;
  float acc = 0.0f;
#pragma unroll
  for (int c = 0; c < 8; ++c) acc += part[(size_t)(b * 8 + c) * DD + d];
  out[(size_t)b * DD + d] = (float)DD * acc;
}

// ---------- launch ----------
extern "C" void kernel_launch(void* const* d_in, const int* in_sizes, int n_in,
                              void* d_out, int out_size, void* d_ws, size_t ws_size,
                              hipStream_t stream) {
  const float* x = (const float*)d_in[0];
  const float* a0p = (const float*)d_in[1];
  const float* a1p = (const float*)d_in[2];
  const float* a2p = (const float*)d_in[3];
  const float* a3p = (const float*)d_in[4];
  const float* rhop = (const float*)d_in[5];
  float* out = (float*)d_out;

  const size_t NE = (size_t)BATCH * NN * DD;  // 4M elements per full field
  const size_t NE_b = (size_t)NN * DD;        // per-batch stride (131072)
  const size_t C2_b = (size_t)NN * NN;        // 262144
  const size_t C1_b = (size_t)DD * DD;        // 65536

  float* fws = (float*)d_ws;
  float* log_t = fws;                 // NE
  float* log_s = fws + NE;            // NE
  float* zb = fws + 2 * NE;           // NE
  float* Gb = fws + 3 * NE;           // NE
  float* part = fws + 4 * NE;         // 64K
  float* P = part + 65536;            // 24
  unsigned* keys = (unsigned*)(P + 24);
  short* sws = (short*)(fws + 4 * NE + 65536 + 64);
  short* xb = sws;                    // NE  (aliased: eS after Gram gemms)
  short* xTb = sws + NE;              // NE  (aliased: eT)
  short* eS = xb;
  short* eT = xTb;
  short* Vt = sws + 2 * NE;           // NE
  short* c1b = sws + 3 * NE;          // B*D*D
  short* c2b = c1b + (size_t)BATCH * C1_b;  // B*N*N

  k_prep<<<dim3(4, 8, BATCH), 256, 0, stream>>>(x, xb, xTb, keys);
  // c2 = x x^T / D  (A=xb, B=xb)
  k_mfma<256, 0><<<dim3(4, 4, BATCH), 256, 0, stream>>>(
      xb, NE_b, DD, xb, NE_b, DD, (void*)c2b, C2_b, NN, 1.0f / DD, keys + 1,
      nullptr, nullptr, nullptr, nullptr, 0);
  // c1 = x^T x / N  (A=xTb, B=xTb)
  k_mfma<512, 0><<<dim3(2, 2, BATCH), 256, 0, stream>>>(
      xTb, NE_b, NN, xTb, NE_b, NN, (void*)c1b, C1_b, DD, 1.0f / NN, keys + 0,
      nullptr, nullptr, nullptr, nullptr, 0);
  k_init<<<2048, 256, 0, stream>>>(log_s, eS, zb);
  k_params<<<1, 1, 0, stream>>>(a0p, a1p, a2p, a3p, rhop, P, keys);

  for (int k = 0; k < NUMK; ++k) {
    // V^T = (eS @ c1)^T
    k_mfma<256, 1><<<dim3(2, 4, BATCH), 256, 0, stream>>>(
        eS, NE_b, DD, c1b, C1_b, DD, (void*)Vt, NE_b, NN, 1.0f, nullptr,
        nullptr, nullptr, nullptr, nullptr, 0);
    // G = (x + a1e*(c2@V) + z + rho*log_s)/(rho+a0)   [computed as V^T @ c2, stored N-layout]
    k_mfma<512, 2><<<dim3(4, 2, BATCH), 256, 0, stream>>>(
        Vt, NE_b, NN, c2b, C2_b, NN, (void*)Gb, NE_b, DD, 1.0f, nullptr,
        x, zb, log_s, P, k);
    k_trow<<<BATCH * NN, 256, 0, stream>>>(Gb, log_t, eT, P, k);
    // V^T = (eT @ c1)^T
    k_mfma<256, 1><<<dim3(2, 4, BATCH), 256, 0, stream>>>(
        eT, NE_b, DD, c1b, C1_b, DD, (void*)Vt, NE_b, NN, 1.0f, nullptr,
        nullptr, nullptr, nullptr, nullptr, 0);
    // G = (a1e*(c2@V) - z + rho*log_t)/rho
    k_mfma<512, 3><<<dim3(4, 2, BATCH), 256, 0, stream>>>(
        Vt, NE_b, NN, c2b, C2_b, NN, (void*)Gb, NE_b, DD, 1.0f, nullptr,
        x, zb, log_t, P, k);
    k_scol<<<128, 1024, 0, stream>>>(Gb, log_t, log_s, eS, zb, P, k);
  }
  k_out1<<<256, 256, 0, stream>>>(x, log_t, part);
  k_out2<<<BATCH, 256, 0, stream>>>(part, out);
}

// Round 3
// 483.294 us; speedup vs baseline: 3.2110x; 1.0660x over previous
//
#include <hip/hip_runtime.h>
#include <math.h>

#define BATCH 32
#define NN 512
#define DD 256
#define NUMK 4

typedef __attribute__((ext_vector_type(8))) short bf16x8;
typedef __attribute__((ext_vector_type(4))) float f32x4;
typedef __attribute__((ext_vector_type(4))) unsigned short u16x4;

__device__ __forceinline__ float softplusf(float v) { return log1pf(expf(v)); }

__device__ __forceinline__ unsigned enc_key(float v) {
  unsigned u = __float_as_uint(v);
  return (u & 0x80000000u) ? ~u : (u | 0x80000000u);
}
__device__ __forceinline__ float dec_key(unsigned k) {
  return (k & 0x80000000u) ? __uint_as_float(k & 0x7fffffffu) : __uint_as_float(~k);
}
__device__ __forceinline__ unsigned short f2b(float f) {
  unsigned u = __float_as_uint(f);
  unsigned r = (u + 0x7fffu + ((u >> 16) & 1u)) >> 16;
  return (unsigned short)r;
}
__device__ __forceinline__ float b2f(unsigned short h) {
  return __uint_as_float(((unsigned)h) << 16);
}

#define GLDS(gp, lp)                                                   \
  __builtin_amdgcn_global_load_lds(                                    \
      (__attribute__((address_space(1))) void*)(void*)(gp),            \
      (__attribute__((address_space(3))) void*)(lp), 16, 0, 0)

// ---------- prep: xb = bf16(x) [n][d], xTb = bf16(x^T) [d][n]; zero max keys ----------
__global__ __launch_bounds__(256) void k_prep(const float* __restrict__ x,
                                              short* __restrict__ xb,
                                              short* __restrict__ xTb,
                                              unsigned* keys) {
  __shared__ float t[64][65];
  int b = blockIdx.z, n0 = blockIdx.y * 64, d0 = blockIdx.x * 64;
  if (blockIdx.x == 0 && blockIdx.y == 0 && blockIdx.z == 0 && threadIdx.x == 0) {
    keys[0] = 0u; keys[1] = 0u;
  }
  const float* X = x + (size_t)b * NN * DD;
  int col = threadIdx.x & 63, rr = threadIdx.x >> 6;
#pragma unroll
  for (int s = 0; s < 16; ++s) {
    int row = s * 4 + rr;
    float v = X[(size_t)(n0 + row) * DD + d0 + col];
    t[row][col] = v;
    xb[(size_t)b * NN * DD + (size_t)(n0 + row) * DD + d0 + col] = (short)f2b(v);
  }
  __syncthreads();
#pragma unroll
  for (int s = 0; s < 16; ++s) {
    int row = s * 4 + rr;  // d within tile
    xTb[(size_t)b * DD * NN + (size_t)(d0 + row) * NN + n0 + col] = (short)f2b(t[col][row]);
  }
}

// ---------- zero the dual z ----------
__global__ void k_initz(float* z) {
  size_t total = (size_t)BATCH * NN * DD;
  for (size_t i = (size_t)blockIdx.x * blockDim.x + threadIdx.x; i < total;
       i += (size_t)gridDim.x * blockDim.x)
    z[i] = 0.0f;
}

// ---------- scalar params + constant marginal recurrences ----------
__global__ void k_params(const float* a0p, const float* a1p, const float* a2p,
                         const float* a3p, const float* rhop, float* P, unsigned* keys) {
  if (threadIdx.x != 0 || blockIdx.x != 0) return;
  float M1 = dec_key(keys[0]);  // max c1
  float M2 = dec_key(keys[1]);  // max c2
  float lq0 = logf(1.0f / NN + 1e-8f);
  float lp0 = logf(1.0f / DD + 1e-8f);
  float mu = lq0, eta = lp0, z1 = 0.f, z2 = 0.f;
  for (int k = 0; k < NUMK; ++k) {
    float a0 = softplusf(a0p[k]), a1 = softplusf(a1p[k]);
    float a2 = softplusf(a2p[k]), a3 = softplusf(a3p[k]);
    float rho = softplusf(rhop[k]);
    P[0 + k] = a0;
    P[4 + k] = a1 / (M1 * M2);
    P[8 + k] = rho;
    P[12 + k] = mu;
    P[16 + k] = eta;
    float t1 = mu;
    mu = (a2 * lq0 + rho * t1 - z1) / (a2 + rho);
    z1 += rho * (expf(mu) - expf(t1));
    float s1 = eta;
    eta = (a3 * lp0 + rho * s1 - z2) / (a3 + rho);
    z2 += rho * (expf(eta) - expf(s1));
  }
}

// ---------- row sums of bf16 matrices (for iter-0 rank-1 shortcut) ----------
__global__ __launch_bounds__(256) void k_rsum512(const short* __restrict__ M,
                                                 float* __restrict__ r) {
  int row = blockIdx.x * 4 + (threadIdx.x >> 6);
  int lane = threadIdx.x & 63;
  bf16x8 v = *(const bf16x8*)(M + (size_t)row * 512 + lane * 8);
  float s = 0.f;
#pragma unroll
  for (int q = 0; q < 8; ++q) s += b2f((unsigned short)v[q]);
#pragma unroll
  for (int o = 32; o > 0; o >>= 1) s += __shfl_xor(s, o);
  if (lane == 0) r[row] = s;
}
__global__ __launch_bounds__(256) void k_rsum256(const short* __restrict__ M,
                                                 float* __restrict__ r) {
  int row = blockIdx.x * 4 + (threadIdx.x >> 6);
  int lane = threadIdx.x & 63;
  u16x4 v = *(const u16x4*)(M + (size_t)row * 256 + lane * 4);
  float s = 0.f;
#pragma unroll
  for (int q = 0; q < 4; ++q) s += b2f(v[q]);
#pragma unroll
  for (int o = 32; o > 0; o >>= 1) s += __shfl_xor(s, o);
  if (lane == 0) r[row] = s;
}

// ---------- unified bf16 MFMA GEMM, 64x64 tile, BK=64, swizzled LDS ----------
// C[m][c] = sum_k A[m][k]*B[c][k]; stored transposed: out[c*ldo + m].
// OUTK 0: bf16 out, *scale, fused global atomicMax     (Gram matrices)
// OUTK 1: bf16 out                                     (V = E @ c1 -> V^T)
// OUTK 2: f32 out w/ epi (x + a1e*W + z + rho*L)/(rho+a0)
// OUTK 3: f32 out w/ epi (a1e*W - z + rho*L)/rho
template <int K, int OUTK>
__global__ __launch_bounds__(256) void k_mfma(
    const short* __restrict__ A, size_t sA, int lda,
    const short* __restrict__ Bp, size_t sB, int ldb,
    void* __restrict__ outp, size_t sO, int ldo,
    float scale, unsigned* maxslot,
    const float* __restrict__ xg, const float* __restrict__ zg,
    const float* __restrict__ Lg, const float* __restrict__ P, int kiter) {
  __shared__ short As[64 * 64];
  __shared__ short Bs[64 * 64];
  const int b = blockIdx.z;
  const int m0 = blockIdx.y * 64, n0 = blockIdx.x * 64;
  const int tid = threadIdx.x, wave = tid >> 6, lane = tid & 63;
  const int ln = lane & 15, kg = lane >> 4;
  const int wr = (wave >> 1) * 32, wc = (wave & 1) * 32;
  const short* Ab = A + (size_t)b * sA;
  const short* Bb = Bp + (size_t)b * sB;
  const int srow = lane >> 3;       // 0..7 row within 8-row chunk
  const int sslot = lane & 7;       // 16B slot within 128B row

  f32x4 acc[2][2];
#pragma unroll
  for (int i = 0; i < 2; ++i)
#pragma unroll
    for (int j = 0; j < 2; ++j) acc[i][j] = (f32x4){0.f, 0.f, 0.f, 0.f};

  for (int k0 = 0; k0 < K; k0 += 64) {
    __syncthreads();
#pragma unroll
    for (int p = 0; p < 2; ++p) {
      int row = p * 32 + wave * 8 + srow;
      int sg = sslot ^ (row & 7);  // pre-swizzled global slot (involution)
      GLDS(Ab + (size_t)(m0 + row) * lda + k0 + sg * 8, &As[(p * 32 + wave * 8) * 64]);
      GLDS(Bb + (size_t)(n0 + row) * ldb + k0 + sg * 8, &Bs[(p * 32 + wave * 8) * 64]);
    }
    __syncthreads();
    bf16x8 af[2][2], bfr[2][2];
#pragma unroll
    for (int i = 0; i < 2; ++i)
#pragma unroll
      for (int kk = 0; kk < 2; ++kk) {
        int rowA = wr + i * 16 + ln;
        af[i][kk] = *(const bf16x8*)&As[rowA * 64 + (((kk * 4 + kg) ^ (rowA & 7)) * 8)];
        int rowB = wc + i * 16 + ln;
        bfr[i][kk] = *(const bf16x8*)&Bs[rowB * 64 + (((kk * 4 + kg) ^ (rowB & 7)) * 8)];
      }
#pragma unroll
    for (int kk = 0; kk < 2; ++kk)
#pragma unroll
      for (int i = 0; i < 2; ++i)
#pragma unroll
        for (int j = 0; j < 2; ++j)
          acc[i][j] = __builtin_amdgcn_mfma_f32_16x16x32_bf16(af[i][kk], bfr[j][kk],
                                                              acc[i][j], 0, 0, 0);
  }

  if (OUTK <= 1) {
    unsigned short* ot = (unsigned short*)outp + (size_t)b * sO;
    float tmax = -1e30f;
#pragma unroll
    for (int i = 0; i < 2; ++i) {
      int r = m0 + wr + i * 16 + kg * 4;
#pragma unroll
      for (int j = 0; j < 2; ++j) {
        int c = n0 + wc + j * 16 + ln;
        u16x4 pk;
#pragma unroll
        for (int q = 0; q < 4; ++q) {
          float v = acc[i][j][q] * scale;
          if (OUTK == 0) tmax = fmaxf(tmax, v);
          pk[q] = f2b(v);
        }
        *(u16x4*)&ot[(size_t)c * ldo + r] = pk;
      }
    }
    if (OUTK == 0) {
#pragma unroll
      for (int o = 32; o > 0; o >>= 1) tmax = fmaxf(tmax, __shfl_xor(tmax, o));
      __syncthreads();
      float* smf = (float*)As;
      if (lane == 0) smf[wave] = tmax;
      __syncthreads();
      if (tid == 0)
        atomicMax(maxslot, enc_key(fmaxf(fmaxf(smf[0], smf[1]), fmaxf(smf[2], smf[3]))));
    }
  } else {
    float* G = (float*)outp + (size_t)b * sO;
    const float* xb_ = xg + (size_t)b * sO;
    const float* zb_ = zg + (size_t)b * sO;
    const float* Lb_ = Lg + (size_t)b * sO;
    const float a0 = P[kiter], a1e = P[4 + kiter], rho = P[8 + kiter];
    const float inv = (OUTK == 2) ? 1.0f / (rho + a0) : 1.0f / rho;
#pragma unroll
    for (int i = 0; i < 2; ++i) {
      int r = m0 + wr + i * 16 + kg * 4;
#pragma unroll
      for (int j = 0; j < 2; ++j) {
        int c = n0 + wc + j * 16 + ln;
        size_t idx = (size_t)c * DD + r;
        f32x4 zv = *(const f32x4*)&zb_[idx];
        f32x4 lv = *(const f32x4*)&Lb_[idx];
        f32x4 o;
        if (OUTK == 2) {
          f32x4 xv = *(const f32x4*)&xb_[idx];
#pragma unroll
          for (int q = 0; q < 4; ++q)
            o[q] = (xv[q] + a1e * acc[i][j][q] + zv[q] + rho * lv[q]) * inv;
        } else {
#pragma unroll
          for (int q = 0; q < 4; ++q)
            o[q] = (a1e * acc[i][j][q] - zv[q] + rho * lv[q]) * inv;
        }
        *(f32x4*)&G[idx] = o;
      }
    }
  }
}

// ---------- T-update: log_t = mu + log_softmax over d; eT = exp(log_t) bf16 ----------
__global__ __launch_bounds__(256) void k_trow(const float* __restrict__ G,
                                              float* __restrict__ log_t,
                                              short* __restrict__ eT,
                                              const float* __restrict__ P, int kiter) {
  size_t row = blockIdx.x;
  float y = G[row * DD + threadIdx.x];
  float m = y;
#pragma unroll
  for (int o = 32; o > 0; o >>= 1) m = fmaxf(m, __shfl_xor(m, o));
  __shared__ float sm[4], ss[4];
  int wv = threadIdx.x >> 6;
  if ((threadIdx.x & 63) == 0) sm[wv] = m;
  __syncthreads();
  m = fmaxf(fmaxf(sm[0], sm[1]), fmaxf(sm[2], sm[3]));
  float sum = expf(y - m);
#pragma unroll
  for (int o = 32; o > 0; o >>= 1) sum += __shfl_xor(sum, o);
  if ((threadIdx.x & 63) == 0) ss[wv] = sum;
  __syncthreads();
  float lse = m + logf(ss[0] + ss[1] + ss[2] + ss[3]);
  float lt = P[12 + kiter] + y - lse;
  log_t[row * DD + threadIdx.x] = lt;
  eT[row * DD + threadIdx.x] = (short)f2b(expf(lt));
}

// ---------- iter-0 T-update via rank-1 gw: y = (x + a1e*e0*r2[n]*s1[d])/(rho+a0) ----------
__global__ __launch_bounds__(256) void k_trow0(const float* __restrict__ x,
                                               const float* __restrict__ r2,
                                               const float* __restrict__ s1,
                                               float* __restrict__ log_t,
                                               short* __restrict__ eT,
                                               const float* __restrict__ P) {
  size_t row = blockIdx.x;  // b*N + n
  int b = (int)(row >> 9);
  const float c0 = logf(1.0f / NN + 1e-8f) + logf(1.0f / DD + 1e-8f);
  float g = P[4] * expf(c0) * r2[row];
  float inv = 1.0f / (P[8] + P[0]);
  float y = (x[row * DD + threadIdx.x] + g * s1[(size_t)b * DD + threadIdx.x]) * inv;
  float m = y;
#pragma unroll
  for (int o = 32; o > 0; o >>= 1) m = fmaxf(m, __shfl_xor(m, o));
  __shared__ float sm[4], ss[4];
  int wv = threadIdx.x >> 6;
  if ((threadIdx.x & 63) == 0) sm[wv] = m;
  __syncthreads();
  m = fmaxf(fmaxf(sm[0], sm[1]), fmaxf(sm[2], sm[3]));
  float sum = expf(y - m);
#pragma unroll
  for (int o = 32; o > 0; o >>= 1) sum += __shfl_xor(sum, o);
  if ((threadIdx.x & 63) == 0) ss[wv] = sum;
  __syncthreads();
  float lse = m + logf(ss[0] + ss[1] + ss[2] + ss[3]);
  float lt = P[12] + y - lse;
  log_t[row * DD + threadIdx.x] = lt;
  eT[row * DD + threadIdx.x] = (short)f2b(expf(lt));
}

// ---------- S-update over n (online LSE) + eS bf16 + fused dual z-update ----------
__global__ __launch_bounds__(1024) void k_scol(const float* __restrict__ G,
                                               const float* __restrict__ log_t,
                                               float* __restrict__ log_s,
                                               short* __restrict__ eS,
                                               float* __restrict__ z,
                                               const float* __restrict__ P, int kiter) {
  int b = blockIdx.x >> 2;
  int d0 = (blockIdx.x & 3) << 6;
  int tx = threadIdx.x & 63;
  int ty = threadIdx.x >> 6;  // 0..15
  int d = d0 + tx;
  size_t base = (size_t)b * NN * DD;
  __shared__ float red_m[16][64], red_s[16][64], lse_s[64];
  float m = -1e30f, s = 0.0f;
  for (int n = ty; n < NN; n += 16) {
    float g = G[base + (size_t)n * DD + d];
    float nm = fmaxf(m, g);
    s = s * expf(m - nm) + expf(g - nm);
    m = nm;
  }
  red_m[ty][tx] = m;
  red_s[ty][tx] = s;
  __syncthreads();
  if (ty == 0) {
    float M = red_m[0][tx], S = red_s[0][tx];
#pragma unroll
    for (int t = 1; t < 16; ++t) {
      float m2 = red_m[t][tx], s2 = red_s[t][tx];
      float nm = fmaxf(M, m2);
      S = S * expf(M - nm) + s2 * expf(m2 - nm);
      M = nm;
    }
    lse_s[tx] = M + logf(S);
  }
  __syncthreads();
  float lse = lse_s[tx];
  float eta = P[16 + kiter], rho = P[8 + kiter];
  for (int n = ty; n < NN; n += 16) {
    size_t idx = base + (size_t)n * DD + d;
    float ls = eta + G[idx] - lse;
    log_s[idx] = ls;
    float es = expf(ls);
    eS[idx] = (short)f2b(es);
    z[idx] += rho * (expf(log_t[idx]) - es);
  }
}

// ---------- output: out[b,d] = D * sum_n x*exp(log_t) ----------
__global__ __launch_bounds__(256) void k_out1(const float* __restrict__ x,
                                              const float* __restrict__ log_t,
                                              float* __restrict__ part) {
  int bc = blockIdx.x;
  int b = bc >> 3, ch = bc & 7;
  int d = threadIdx.x;
  size_t base = (size_t)b * NN * DD;
  float acc = 0.0f;
  for (int n = ch * 64; n < ch * 64 + 64; ++n) {
    size_t idx = base + (size_t)n * DD + d;
    acc += x[idx] * expf(log_t[idx]);
  }
  part[(size_t)bc * DD + d] = acc;
}
__global__ __launch_bounds__(256) void k_out2(const float* __restrict__ part,
                                              float* __restrict__ out) {
  int b = blockIdx.x, d = threadIdx.x;
  float acc = 0.0f;
#pragma unroll
  for (int c = 0; c < 8; ++c) acc += part[(size_t)(b * 8 + c) * DD + d];
  out[(size_t)b * DD + d] = (float)DD * acc;
}

// ---------- launch ----------
extern "C" void kernel_launch(void* const* d_in, const int* in_sizes, int n_in,
                              void* d_out, int out_size, void* d_ws, size_t ws_size,
                              hipStream_t stream) {
  const float* x = (const float*)d_in[0];
  const float* a0p = (const float*)d_in[1];
  const float* a1p = (const float*)d_in[2];
  const float* a2p = (const float*)d_in[3];
  const float* a3p = (const float*)d_in[4];
  const float* rhop = (const float*)d_in[5];
  float* out = (float*)d_out;

  const size_t NE = (size_t)BATCH * NN * DD;
  const size_t NE_b = (size_t)NN * DD;
  const size_t C2_b = (size_t)NN * NN;
  const size_t C1_b = (size_t)DD * DD;

  float* fws = (float*)d_ws;
  float* log_t = fws;            // NE
  float* log_s = fws + NE;       // NE
  float* zb = fws + 2 * NE;      // NE
  float* Gb = fws + 3 * NE;      // NE
  float* part = fws + 4 * NE;    // 64K
  float* r2 = part + 65536;      // B*N
  float* s1 = r2 + BATCH * NN;   // B*D
  float* P = s1 + BATCH * DD;    // 24
  unsigned* keys = (unsigned*)(P + 24);
  short* sws = (short*)(keys + 8);
  short* xb = sws;               // NE   (aliased: eS)
  short* xTb = sws + NE;         // NE   (aliased: eT)
  short* eS = xb;
  short* eT = xTb;
  short* Vt = sws + 2 * NE;      // NE
  short* c1b = sws + 3 * NE;     // B*D*D
  short* c2b = c1b + (size_t)BATCH * C1_b;  // B*N*N

  k_prep<<<dim3(4, 8, BATCH), 256, 0, stream>>>(x, xb, xTb, keys);
  // c2 = x x^T / D
  k_mfma<256, 0><<<dim3(8, 8, BATCH), 256, 0, stream>>>(
      xb, NE_b, DD, xb, NE_b, DD, (void*)c2b, C2_b, NN, 1.0f / DD, keys + 1,
      nullptr, nullptr, nullptr, nullptr, 0);
  // c1 = x^T x / N
  k_mfma<512, 0><<<dim3(4, 4, BATCH), 256, 0, stream>>>(
      xTb, NE_b, NN, xTb, NE_b, NN, (void*)c1b, C1_b, DD, 1.0f / NN, keys + 0,
      nullptr, nullptr, nullptr, nullptr, 0);
  k_rsum512<<<BATCH * NN / 4, 256, 0, stream>>>(c2b, r2);
  k_rsum256<<<BATCH * DD / 4, 256, 0, stream>>>(c1b, s1);
  k_initz<<<1024, 256, 0, stream>>>(zb);
  k_params<<<1, 1, 0, stream>>>(a0p, a1p, a2p, a3p, rhop, P, keys);

  for (int k = 0; k < NUMK; ++k) {
    if (k == 0) {
      // rank-1 shortcut: gw = a1e*e0 * r2 (x) s1; log_s/eS are constant
      k_trow0<<<BATCH * NN, 256, 0, stream>>>(x, r2, s1, log_t, eT, P);
    } else {
      k_mfma<256, 1><<<dim3(4, 8, BATCH), 256, 0, stream>>>(
          eS, NE_b, DD, c1b, C1_b, DD, (void*)Vt, NE_b, NN, 1.0f, nullptr,
          nullptr, nullptr, nullptr, nullptr, 0);
      k_mfma<512, 2><<<dim3(8, 4, BATCH), 256, 0, stream>>>(
          Vt, NE_b, NN, c2b, C2_b, NN, (void*)Gb, NE_b, DD, 1.0f, nullptr,
          x, zb, log_s, P, k);
      k_trow<<<BATCH * NN, 256, 0, stream>>>(Gb, log_t, eT, P, k);
    }
    k_mfma<256, 1><<<dim3(4, 8, BATCH), 256, 0, stream>>>(
        eT, NE_b, DD, c1b, C1_b, DD, (void*)Vt, NE_b, NN, 1.0f, nullptr,
        nullptr, nullptr, nullptr, nullptr, 0);
    k_mfma<512, 3><<<dim3(8, 4, BATCH), 256, 0, stream>>>(
        Vt, NE_b, NN, c2b, C2_b, NN, (void*)Gb, NE_b, DD, 1.0f, nullptr,
        x, zb, log_t, P, k);
    k_scol<<<128, 1024, 0, stream>>>(Gb, log_t, log_s, eS, zb, P, k);
  }
  k_out1<<<256, 256, 0, stream>>>(x, log_t, part);
  k_out2<<<BATCH, 256, 0, stream>>>(part, out);
}

// Round 4
// 360.742 us; speedup vs baseline: 4.3019x; 1.3397x over previous
//
#include <hip/hip_runtime.h>
#include <math.h>

#define BATCH 32
#define NN 512
#define DD 256
#define NUMK 4

typedef __attribute__((ext_vector_type(8))) short bf16x8;
typedef __attribute__((ext_vector_type(4))) float f32x4;
typedef __attribute__((ext_vector_type(4))) unsigned short u16x4;

__device__ __forceinline__ float softplusf(float v) { return log1pf(expf(v)); }

__device__ __forceinline__ unsigned enc_key(float v) {
  unsigned u = __float_as_uint(v);
  return (u & 0x80000000u) ? ~u : (u | 0x80000000u);
}
__device__ __forceinline__ float dec_key(unsigned k) {
  return (k & 0x80000000u) ? __uint_as_float(k & 0x7fffffffu) : __uint_as_float(~k);
}
__device__ __forceinline__ unsigned short f2b(float f) {
  unsigned u = __float_as_uint(f);
  unsigned r = (u + 0x7fffu + ((u >> 16) & 1u)) >> 16;
  return (unsigned short)r;
}
__device__ __forceinline__ float b2f(unsigned short h) {
  return __uint_as_float(((unsigned)h) << 16);
}
__device__ __forceinline__ int kx4(int r) { return (r ^ (r >> 2)) & 3; }

#define GLDS(gp, lp)                                                   \
  __builtin_amdgcn_global_load_lds(                                    \
      (__attribute__((address_space(1))) void*)(void*)(gp),            \
      (__attribute__((address_space(3))) void*)(lp), 16, 0, 0)

// ---------- prep: xb = bf16(x) [n][d], xTb = bf16(x^T) [d][n]; zero max keys ----------
__global__ __launch_bounds__(256) void k_prep(const float* __restrict__ x,
                                              short* __restrict__ xb,
                                              short* __restrict__ xTb,
                                              unsigned* keys) {
  __shared__ float t[64][65];
  int b = blockIdx.z, n0 = blockIdx.y * 64, d0 = blockIdx.x * 64;
  if (blockIdx.x == 0 && blockIdx.y == 0 && blockIdx.z == 0 && threadIdx.x == 0) {
    keys[0] = 0u; keys[1] = 0u;
  }
  const float* X = x + (size_t)b * NN * DD;
  int col = threadIdx.x & 63, rr = threadIdx.x >> 6;
#pragma unroll
  for (int s = 0; s < 16; ++s) {
    int row = s * 4 + rr;
    float v = X[(size_t)(n0 + row) * DD + d0 + col];
    t[row][col] = v;
    xb[(size_t)b * NN * DD + (size_t)(n0 + row) * DD + d0 + col] = (short)f2b(v);
  }
  __syncthreads();
#pragma unroll
  for (int s = 0; s < 16; ++s) {
    int row = s * 4 + rr;  // d within tile
    xTb[(size_t)b * DD * NN + (size_t)(d0 + row) * NN + n0 + col] = (short)f2b(t[col][row]);
  }
}

// ---------- Gram / V GEMM: 64x64 tile, BK=64, swizzled LDS ----------
// C[m][c] = sum_k A[m][k]*B[c][k]; stored transposed: out[c*ldo + m].
// OUTK 0: bf16 out, *scale, fused global atomicMax  (Gram)
// OUTK 1: bf16 out                                  (V^T = (E @ c1)^T)
template <int K, int OUTK>
__global__ __launch_bounds__(256) void k_gemm(
    const short* __restrict__ A, size_t sA, int lda,
    const short* __restrict__ Bp, size_t sB, int ldb,
    void* __restrict__ outp, size_t sO, int ldo,
    float scale, unsigned* maxslot) {
  __shared__ short As[64 * 64];
  __shared__ short Bs[64 * 64];
  const int b = blockIdx.z;
  const int m0 = blockIdx.y * 64, n0 = blockIdx.x * 64;
  const int tid = threadIdx.x, wave = tid >> 6, lane = tid & 63;
  const int ln = lane & 15, kg = lane >> 4;
  const int wr = (wave >> 1) * 32, wc = (wave & 1) * 32;
  const short* Ab = A + (size_t)b * sA;
  const short* Bb = Bp + (size_t)b * sB;
  const int srow = lane >> 3;
  const int sslot = lane & 7;

  f32x4 acc[2][2];
#pragma unroll
  for (int i = 0; i < 2; ++i)
#pragma unroll
    for (int j = 0; j < 2; ++j) acc[i][j] = (f32x4){0.f, 0.f, 0.f, 0.f};

  for (int k0 = 0; k0 < K; k0 += 64) {
    __syncthreads();
#pragma unroll
    for (int p = 0; p < 2; ++p) {
      int row = p * 32 + wave * 8 + srow;
      int sg = sslot ^ (row & 7);
      GLDS(Ab + (size_t)(m0 + row) * lda + k0 + sg * 8, &As[(p * 32 + wave * 8) * 64]);
      GLDS(Bb + (size_t)(n0 + row) * ldb + k0 + sg * 8, &Bs[(p * 32 + wave * 8) * 64]);
    }
    __syncthreads();
    bf16x8 af[2][2], bfr[2][2];
#pragma unroll
    for (int i = 0; i < 2; ++i)
#pragma unroll
      for (int kk = 0; kk < 2; ++kk) {
        int rowA = wr + i * 16 + ln;
        af[i][kk] = *(const bf16x8*)&As[rowA * 64 + (((kk * 4 + kg) ^ (rowA & 7)) * 8)];
        int rowB = wc + i * 16 + ln;
        bfr[i][kk] = *(const bf16x8*)&Bs[rowB * 64 + (((kk * 4 + kg) ^ (rowB & 7)) * 8)];
      }
#pragma unroll
    for (int kk = 0; kk < 2; ++kk)
#pragma unroll
      for (int i = 0; i < 2; ++i)
#pragma unroll
        for (int j = 0; j < 2; ++j)
          acc[i][j] = __builtin_amdgcn_mfma_f32_16x16x32_bf16(af[i][kk], bfr[j][kk],
                                                              acc[i][j], 0, 0, 0);
  }

  unsigned short* ot = (unsigned short*)outp + (size_t)b * sO;
  float tmax = -1e30f;
#pragma unroll
  for (int i = 0; i < 2; ++i) {
    int r = m0 + wr + i * 16 + kg * 4;
#pragma unroll
    for (int j = 0; j < 2; ++j) {
      int c = n0 + wc + j * 16 + ln;
      u16x4 pk;
#pragma unroll
      for (int q = 0; q < 4; ++q) {
        float v = acc[i][j][q] * scale;
        if (OUTK == 0) tmax = fmaxf(tmax, v);
        pk[q] = f2b(v);
      }
      *(u16x4*)&ot[(size_t)c * ldo + r] = pk;
    }
  }
  if (OUTK == 0) {
#pragma unroll
    for (int o = 32; o > 0; o >>= 1) tmax = fmaxf(tmax, __shfl_xor(tmax, o));
    __syncthreads();
    float* smf = (float*)As;
    if (lane == 0) smf[wave] = tmax;
    __syncthreads();
    if (tid == 0)
      atomicMax(maxslot, enc_key(fmaxf(fmaxf(smf[0], smf[1]), fmaxf(smf[2], smf[3]))));
  }
}

// ---------- misc: row sums of c2/c1 + scalar params, one launch ----------
__global__ __launch_bounds__(256) void k_misc(const short* __restrict__ c2b,
                                              const short* __restrict__ c1b,
                                              float* __restrict__ r2,
                                              float* __restrict__ s1,
                                              const float* a0p, const float* a1p,
                                              const float* a2p, const float* a3p,
                                              const float* rhop, float* P,
                                              const unsigned* keys) {
  int bid = blockIdx.x;
  int lane = threadIdx.x & 63;
  if (bid < 4096) {  // c2 row sums (16384 rows, 4/block)
    int row = bid * 4 + (threadIdx.x >> 6);
    bf16x8 v = *(const bf16x8*)(c2b + (size_t)row * 512 + lane * 8);
    float s = 0.f;
#pragma unroll
    for (int q = 0; q < 8; ++q) s += b2f((unsigned short)v[q]);
#pragma unroll
    for (int o = 32; o > 0; o >>= 1) s += __shfl_xor(s, o);
    if (lane == 0) r2[row] = s;
  } else if (bid < 6144) {  // c1 row sums (8192 rows)
    int row = (bid - 4096) * 4 + (threadIdx.x >> 6);
    u16x4 v = *(const u16x4*)(c1b + (size_t)row * 256 + lane * 4);
    float s = 0.f;
#pragma unroll
    for (int q = 0; q < 4; ++q) s += b2f(v[q]);
#pragma unroll
    for (int o = 32; o > 0; o >>= 1) s += __shfl_xor(s, o);
    if (lane == 0) s1[row] = s;
  } else if (threadIdx.x == 0) {  // params
    float M1 = dec_key(keys[0]);
    float M2 = dec_key(keys[1]);
    float lq0 = logf(1.0f / NN + 1e-8f);
    float lp0 = logf(1.0f / DD + 1e-8f);
    float mu = lq0, eta = lp0, z1 = 0.f, z2 = 0.f;
    for (int k = 0; k < NUMK; ++k) {
      float a0 = softplusf(a0p[k]), a1 = softplusf(a1p[k]);
      float a2 = softplusf(a2p[k]), a3 = softplusf(a3p[k]);
      float rho = softplusf(rhop[k]);
      P[0 + k] = a0;
      P[4 + k] = a1 / (M1 * M2);
      P[8 + k] = rho;
      P[12 + k] = mu;
      P[16 + k] = eta;
      float t1 = mu;
      mu = (a2 * lq0 + rho * t1 - z1) / (a2 + rho);
      z1 += rho * (expf(mu) - expf(t1));
      float s1v = eta;
      eta = (a3 * lp0 + rho * s1v - z2) / (a3 + rho);
      z2 += rho * (expf(eta) - expf(s1v));
    }
  }
}

// ---------- iter-0 T-update via rank-1 gw ----------
__global__ __launch_bounds__(256) void k_trow0(const float* __restrict__ x,
                                               const float* __restrict__ r2,
                                               const float* __restrict__ s1,
                                               float* __restrict__ log_t,
                                               short* __restrict__ eT,
                                               const float* __restrict__ P) {
  size_t row = blockIdx.x;  // b*N + n
  int b = (int)(row >> 9);
  const float c0 = logf(1.0f / NN + 1e-8f) + logf(1.0f / DD + 1e-8f);
  float g = P[4] * expf(c0) * r2[row];
  float inv = 1.0f / (P[8] + P[0]);
  float y = (x[row * DD + threadIdx.x] + g * s1[(size_t)b * DD + threadIdx.x]) * inv;
  float m = y;
#pragma unroll
  for (int o = 32; o > 0; o >>= 1) m = fmaxf(m, __shfl_xor(m, o));
  __shared__ float sm[4], ss[4];
  int wv = threadIdx.x >> 6;
  if ((threadIdx.x & 63) == 0) sm[wv] = m;
  __syncthreads();
  m = fmaxf(fmaxf(sm[0], sm[1]), fmaxf(sm[2], sm[3]));
  float sum = expf(y - m);
#pragma unroll
  for (int o = 32; o > 0; o >>= 1) sum += __shfl_xor(sum, o);
  if ((threadIdx.x & 63) == 0) ss[wv] = sum;
  __syncthreads();
  float lse = m + logf(ss[0] + ss[1] + ss[2] + ss[3]);
  float lt = P[12] + y - lse;
  log_t[row * DD + threadIdx.x] = lt;
  eT[row * DD + threadIdx.x] = (short)f2b(expf(lt));
}

// ---------- F2: fused y-GEMM + T-softmax (axis=d). Block: all 256 d x 32 n ----------
// y[n][d] = (x + a1e*(Vt . c2) + z + rho*log_s)/(rho+a0); log_t = mu + logsoftmax_d(y)
// LAST: emit per-block output partials instead of log_t/eT.
template <int LAST>
__global__ __launch_bounds__(256) void k_f2(
    const short* __restrict__ Vt, const short* __restrict__ c2b,
    const float* __restrict__ x, const float* __restrict__ z,
    const float* __restrict__ log_s, float* __restrict__ log_t,
    short* __restrict__ eT, float* __restrict__ part,
    const float* __restrict__ P, int kiter) {
  __shared__ short As[256 * 64];  // Vt rows (d) x k chunk (32 KB)
  __shared__ short Bs[32 * 64];   // c2 rows (n) x k chunk (4 KB)
  const int b = blockIdx.y;
  const int n0 = blockIdx.x * 32;
  const int tid = threadIdx.x, wave = tid >> 6, lane = tid & 63;
  const int ln = lane & 15, kg = lane >> 4;
  const short* Av = Vt + (size_t)b * ((size_t)NN * DD);
  const short* Bv = c2b + (size_t)b * ((size_t)NN * NN);
  const size_t base = (size_t)b * ((size_t)NN * DD);

  f32x4 acc[4][2];
#pragma unroll
  for (int i = 0; i < 4; ++i)
#pragma unroll
    for (int j = 0; j < 2; ++j) acc[i][j] = (f32x4){0.f, 0.f, 0.f, 0.f};

  for (int k0 = 0; k0 < NN; k0 += 64) {
    __syncthreads();
#pragma unroll
    for (int cc = 0; cc < 8; ++cc) {
      int row = wave * 64 + cc * 8 + (lane >> 3);
      int sg = (lane & 7) ^ (row & 7);
      GLDS(Av + (size_t)row * NN + k0 + sg * 8, &As[(wave * 64 + cc * 8) * 64]);
    }
    if (wave < 4) {
      int row = wave * 8 + (lane >> 3);
      int sg = (lane & 7) ^ (row & 7);
      GLDS(Bv + (size_t)(n0 + row) * NN + k0 + sg * 8, &Bs[(wave * 8) * 64]);
    }
    __syncthreads();
    bf16x8 af[4][2], bfr[2][2];
#pragma unroll
    for (int i = 0; i < 4; ++i)
#pragma unroll
      for (int kk = 0; kk < 2; ++kk) {
        int rowA = wave * 64 + i * 16 + ln;
        af[i][kk] = *(const bf16x8*)&As[rowA * 64 + (((kk * 4 + kg) ^ (rowA & 7)) * 8)];
      }
#pragma unroll
    for (int j = 0; j < 2; ++j)
#pragma unroll
      for (int kk = 0; kk < 2; ++kk) {
        int rowB = j * 16 + ln;
        bfr[j][kk] = *(const bf16x8*)&Bs[rowB * 64 + (((kk * 4 + kg) ^ (rowB & 7)) * 8)];
      }
#pragma unroll
    for (int kk = 0; kk < 2; ++kk)
#pragma unroll
      for (int i = 0; i < 4; ++i)
#pragma unroll
        for (int j = 0; j < 2; ++j)
          acc[i][j] = __builtin_amdgcn_mfma_f32_16x16x32_bf16(af[i][kk], bfr[j][kk],
                                                              acc[i][j], 0, 0, 0);
  }
  __syncthreads();  // LDS now reusable for reductions
  float* red = (float*)As;  // [4 waves][32 c]

  const float a0 = P[kiter], a1e = P[4 + kiter], rho = P[8 + kiter], mu = P[12 + kiter];
  const float inv = 1.0f / (rho + a0);
  // epilogue: y into acc
#pragma unroll
  for (int i = 0; i < 4; ++i) {
    int r = wave * 64 + i * 16 + kg * 4;
#pragma unroll
    for (int j = 0; j < 2; ++j) {
      int c = n0 + j * 16 + ln;
      size_t idx = base + (size_t)c * DD + r;
      f32x4 xv = *(const f32x4*)&x[idx];
      f32x4 zv = *(const f32x4*)&z[idx];
      f32x4 lv = *(const f32x4*)&log_s[idx];
#pragma unroll
      for (int q = 0; q < 4; ++q)
        acc[i][j][q] = (xv[q] + a1e * acc[i][j][q] + zv[q] + rho * lv[q]) * inv;
    }
  }
  // softmax over d (per c): in-lane (i,q) -> kg (shfl) -> wave (LDS)
  float pm[2], mc[2], ps[2], lse[2];
#pragma unroll
  for (int j = 0; j < 2; ++j) {
    float m = -1e30f;
#pragma unroll
    for (int i = 0; i < 4; ++i)
#pragma unroll
      for (int q = 0; q < 4; ++q) m = fmaxf(m, acc[i][j][q]);
    m = fmaxf(m, __shfl_xor(m, 16));
    m = fmaxf(m, __shfl_xor(m, 32));
    pm[j] = m;
  }
  if (lane < 16) {
    red[wave * 32 + lane] = pm[0];
    red[wave * 32 + 16 + lane] = pm[1];
  }
  __syncthreads();
#pragma unroll
  for (int j = 0; j < 2; ++j)
    mc[j] = fmaxf(fmaxf(red[j * 16 + ln], red[32 + j * 16 + ln]),
                  fmaxf(red[64 + j * 16 + ln], red[96 + j * 16 + ln]));
  __syncthreads();
#pragma unroll
  for (int j = 0; j < 2; ++j) {
    float s = 0.f;
#pragma unroll
    for (int i = 0; i < 4; ++i)
#pragma unroll
      for (int q = 0; q < 4; ++q) s += expf(acc[i][j][q] - mc[j]);
    s += __shfl_xor(s, 16);
    s += __shfl_xor(s, 32);
    ps[j] = s;
  }
  if (lane < 16) {
    red[wave * 32 + lane] = ps[0];
    red[wave * 32 + 16 + lane] = ps[1];
  }
  __syncthreads();
#pragma unroll
  for (int j = 0; j < 2; ++j)
    lse[j] = mc[j] + logf(red[j * 16 + ln] + red[32 + j * 16 + ln] +
                          red[64 + j * 16 + ln] + red[96 + j * 16 + ln]);

  if (LAST == 0) {
#pragma unroll
    for (int i = 0; i < 4; ++i) {
      int r = wave * 64 + i * 16 + kg * 4;
#pragma unroll
      for (int j = 0; j < 2; ++j) {
        int c = n0 + j * 16 + ln;
        size_t idx = base + (size_t)c * DD + r;
        f32x4 lt;
        u16x4 et;
#pragma unroll
        for (int q = 0; q < 4; ++q) {
          float v = mu + acc[i][j][q] - lse[j];
          lt[q] = v;
          et[q] = f2b(expf(v));
        }
        *(f32x4*)&log_t[idx] = lt;
        *(u16x4*)&eT[idx] = et;
      }
    }
  } else {
    // final iteration: out-partials p[d] = sum_n x * exp(log_t)
    const size_t pbase = ((size_t)b * 16 + blockIdx.x) * DD;
#pragma unroll
    for (int i = 0; i < 4; ++i) {
      int r = wave * 64 + i * 16 + kg * 4;
      float p0 = 0.f, p1 = 0.f, p2 = 0.f, p3 = 0.f;
#pragma unroll
      for (int j = 0; j < 2; ++j) {
        int c = n0 + j * 16 + ln;
        size_t idx = base + (size_t)c * DD + r;
        f32x4 xv = *(const f32x4*)&x[idx];
        p0 += expf(mu + acc[i][j][0] - lse[j]) * xv[0];
        p1 += expf(mu + acc[i][j][1] - lse[j]) * xv[1];
        p2 += expf(mu + acc[i][j][2] - lse[j]) * xv[2];
        p3 += expf(mu + acc[i][j][3] - lse[j]) * xv[3];
      }
#pragma unroll
      for (int o = 1; o < 16; o <<= 1) {
        p0 += __shfl_xor(p0, o);
        p1 += __shfl_xor(p1, o);
        p2 += __shfl_xor(p2, o);
        p3 += __shfl_xor(p3, o);
      }
      if (ln == 0) {
        part[pbase + r + 0] = p0;
        part[pbase + r + 1] = p1;
        part[pbase + r + 2] = p2;
        part[pbase + r + 3] = p3;
      }
    }
  }
}

// ---------- F3: fused y2-GEMM + S-softmax (axis=n) + dual z-update ----------
// Block: 32 d x all 512 n. 8 waves; wave w owns c in [w*64, w*64+64). BK=32.
template <int ZFIRST>
__global__ __launch_bounds__(512) void k_f3(
    const short* __restrict__ Vt, const short* __restrict__ c2b,
    const float* __restrict__ log_t, const short* __restrict__ eT,
    float* __restrict__ log_s, short* __restrict__ eS, float* __restrict__ z,
    const float* __restrict__ P, int kiter) {
  __shared__ short As[32 * 32];   // Vt rows (d) x k (2 KB)
  __shared__ short Bs[512 * 32];  // c2 rows (n) x k (32 KB)
  const int b = blockIdx.y;
  const int m0 = blockIdx.x * 32;
  const int tid = threadIdx.x, wave = tid >> 6, lane = tid & 63;
  const int ln = lane & 15, kg = lane >> 4;
  const short* Av = Vt + (size_t)b * ((size_t)NN * DD);
  const short* Bv = c2b + (size_t)b * ((size_t)NN * NN);
  const size_t base = (size_t)b * ((size_t)NN * DD);

  f32x4 acc[2][4];
#pragma unroll
  for (int i = 0; i < 2; ++i)
#pragma unroll
    for (int j = 0; j < 4; ++j) acc[i][j] = (f32x4){0.f, 0.f, 0.f, 0.f};

  for (int k0 = 0; k0 < NN; k0 += 32) {
    __syncthreads();
    if (wave < 2) {
      int row = wave * 16 + (lane >> 2);
      int sg = (lane & 3) ^ kx4(row);
      GLDS(Av + (size_t)(m0 + row) * NN + k0 + sg * 8, &As[(wave * 16) * 32]);
    }
#pragma unroll
    for (int cc = 0; cc < 4; ++cc) {
      int row = wave * 64 + cc * 16 + (lane >> 2);
      int sg = (lane & 3) ^ kx4(row);
      GLDS(Bv + (size_t)row * NN + k0 + sg * 8, &Bs[(wave * 64 + cc * 16) * 32]);
    }
    __syncthreads();
    bf16x8 af[2], bfr[4];
#pragma unroll
    for (int i = 0; i < 2; ++i) {
      int rowA = i * 16 + ln;
      af[i] = *(const bf16x8*)&As[rowA * 32 + ((kg ^ kx4(rowA)) * 8)];
    }
#pragma unroll
    for (int j = 0; j < 4; ++j) {
      int rowB = wave * 64 + j * 16 + ln;
      bfr[j] = *(const bf16x8*)&Bs[rowB * 32 + ((kg ^ kx4(rowB)) * 8)];
    }
#pragma unroll
    for (int i = 0; i < 2; ++i)
#pragma unroll
      for (int j = 0; j < 4; ++j)
        acc[i][j] = __builtin_amdgcn_mfma_f32_16x16x32_bf16(af[i], bfr[j], acc[i][j], 0, 0, 0);
  }
  __syncthreads();
  float* red = (float*)As;  // 512 floats: [0..255] partials, [256..287] max, [288..319] lse

  const float a1e = P[4 + kiter], rho = P[8 + kiter], eta = P[16 + kiter];
  const float invr = 1.0f / rho;
  // epilogue: y2 into acc
#pragma unroll
  for (int i = 0; i < 2; ++i) {
    int r = m0 + i * 16 + kg * 4;
#pragma unroll
    for (int j = 0; j < 4; ++j) {
      int c = wave * 64 + j * 16 + ln;
      size_t idx = base + (size_t)c * DD + r;
      f32x4 lv = *(const f32x4*)&log_t[idx];
      f32x4 zv;
      if (ZFIRST) zv = (f32x4){0.f, 0.f, 0.f, 0.f};
      else zv = *(const f32x4*)&z[idx];
#pragma unroll
      for (int q = 0; q < 4; ++q)
        acc[i][j][q] = (a1e * acc[i][j][q] - zv[q] + rho * lv[q]) * invr;
    }
  }
  // softmax over n (per d): in-lane j -> ln (shfl 1..8) -> wave (LDS)
  float pm[2][4];
#pragma unroll
  for (int i = 0; i < 2; ++i)
#pragma unroll
    for (int q = 0; q < 4; ++q) {
      float m = fmaxf(fmaxf(acc[i][0][q], acc[i][1][q]), fmaxf(acc[i][2][q], acc[i][3][q]));
#pragma unroll
      for (int o = 1; o < 16; o <<= 1) m = fmaxf(m, __shfl_xor(m, o));
      pm[i][q] = m;
    }
  if (ln == 0) {
#pragma unroll
    for (int i = 0; i < 2; ++i)
#pragma unroll
      for (int q = 0; q < 4; ++q) red[wave * 32 + i * 16 + kg * 4 + q] = pm[i][q];
  }
  __syncthreads();
  if (tid < 32) {
    float M = -1e30f;
#pragma unroll
    for (int w = 0; w < 8; ++w) M = fmaxf(M, red[w * 32 + tid]);
    red[256 + tid] = M;
  }
  __syncthreads();
  float mc[2][4], ps[2][4];
#pragma unroll
  for (int i = 0; i < 2; ++i)
#pragma unroll
    for (int q = 0; q < 4; ++q) {
      mc[i][q] = red[256 + i * 16 + kg * 4 + q];
      float s = expf(acc[i][0][q] - mc[i][q]) + expf(acc[i][1][q] - mc[i][q]) +
                expf(acc[i][2][q] - mc[i][q]) + expf(acc[i][3][q] - mc[i][q]);
#pragma unroll
      for (int o = 1; o < 16; o <<= 1) s += __shfl_xor(s, o);
      ps[i][q] = s;
    }
  __syncthreads();
  if (ln == 0) {
#pragma unroll
    for (int i = 0; i < 2; ++i)
#pragma unroll
      for (int q = 0; q < 4; ++q) red[wave * 32 + i * 16 + kg * 4 + q] = ps[i][q];
  }
  __syncthreads();
  if (tid < 32) {
    float S = 0.f;
#pragma unroll
    for (int w = 0; w < 8; ++w) S += red[w * 32 + tid];
    red[288 + tid] = red[256 + tid] + logf(S);
  }
  __syncthreads();
  float lsev[2][4];
#pragma unroll
  for (int i = 0; i < 2; ++i)
#pragma unroll
    for (int q = 0; q < 4; ++q) lsev[i][q] = red[288 + i * 16 + kg * 4 + q];

  // final: log_s, eS, z-update
#pragma unroll
  for (int i = 0; i < 2; ++i) {
    int r = m0 + i * 16 + kg * 4;
#pragma unroll
    for (int j = 0; j < 4; ++j) {
      int c = wave * 64 + j * 16 + ln;
      size_t idx = base + (size_t)c * DD + r;
      f32x4 ls, esf;
      u16x4 ev;
#pragma unroll
      for (int q = 0; q < 4; ++q) {
        float v = eta + acc[i][j][q] - lsev[i][q];
        ls[q] = v;
        float e = expf(v);
        esf[q] = e;
        ev[q] = f2b(e);
      }
      *(f32x4*)&log_s[idx] = ls;
      *(u16x4*)&eS[idx] = ev;
      f32x4 zv;
      if (ZFIRST) zv = (f32x4){0.f, 0.f, 0.f, 0.f};
      else zv = *(const f32x4*)&z[idx];
      u16x4 et = *(const u16x4*)&eT[idx];
      f32x4 zo;
#pragma unroll
      for (int q = 0; q < 4; ++q) zo[q] = zv[q] + rho * (b2f(et[q]) - esf[q]);
      *(f32x4*)&z[idx] = zo;
    }
  }
}

// ---------- final reduce: out[b][d] = D * sum over 16 partial chunks ----------
__global__ __launch_bounds__(256) void k_out2(const float* __restrict__ part,
                                              float* __restrict__ out) {
  int b = blockIdx.x, d = threadIdx.x;
  float acc = 0.0f;
#pragma unroll
  for (int c = 0; c < 16; ++c) acc += part[((size_t)b * 16 + c) * DD + d];
  out[(size_t)b * DD + d] = (float)DD * acc;
}

// ---------- launch ----------
extern "C" void kernel_launch(void* const* d_in, const int* in_sizes, int n_in,
                              void* d_out, int out_size, void* d_ws, size_t ws_size,
                              hipStream_t stream) {
  const float* x = (const float*)d_in[0];
  const float* a0p = (const float*)d_in[1];
  const float* a1p = (const float*)d_in[2];
  const float* a2p = (const float*)d_in[3];
  const float* a3p = (const float*)d_in[4];
  const float* rhop = (const float*)d_in[5];
  float* out = (float*)d_out;

  const size_t NE = (size_t)BATCH * NN * DD;
  const size_t NE_b = (size_t)NN * DD;
  const size_t C2_b = (size_t)NN * NN;
  const size_t C1_b = (size_t)DD * DD;

  float* fws = (float*)d_ws;
  float* log_t = fws;              // NE
  float* log_s = fws + NE;         // NE
  float* zb = fws + 2 * NE;        // NE
  float* part = fws + 3 * NE;      // B*16*DD = 131072
  float* r2 = part + 131072;       // B*N
  float* s1 = r2 + BATCH * NN;     // B*D
  float* P = s1 + BATCH * DD;      // 24
  unsigned* keys = (unsigned*)(P + 24);
  short* sws = (short*)(keys + 8);
  short* xb = sws;                 // NE (aliased: eS)
  short* xTb = sws + NE;           // NE (aliased: eT)
  short* eS = xb;
  short* eT = xTb;
  short* Vt = sws + 2 * NE;        // NE
  short* c1b = sws + 3 * NE;       // B*D*D
  short* c2b = c1b + (size_t)BATCH * C1_b;  // B*N*N

  k_prep<<<dim3(4, 8, BATCH), 256, 0, stream>>>(x, xb, xTb, keys);
  k_gemm<256, 0><<<dim3(8, 8, BATCH), 256, 0, stream>>>(
      xb, NE_b, DD, xb, NE_b, DD, (void*)c2b, C2_b, NN, 1.0f / DD, keys + 1);
  k_gemm<512, 0><<<dim3(4, 4, BATCH), 256, 0, stream>>>(
      xTb, NE_b, NN, xTb, NE_b, NN, (void*)c1b, C1_b, DD, 1.0f / NN, keys + 0);
  k_misc<<<6145, 256, 0, stream>>>(c2b, c1b, r2, s1, a0p, a1p, a2p, a3p, rhop, P, keys);

  // k = 0: rank-1 T-update, then S-half
  k_trow0<<<BATCH * NN, 256, 0, stream>>>(x, r2, s1, log_t, eT, P);
  k_gemm<256, 1><<<dim3(4, 8, BATCH), 256, 0, stream>>>(
      eT, NE_b, DD, c1b, C1_b, DD, (void*)Vt, NE_b, NN, 1.0f, nullptr);
  k_f3<1><<<dim3(8, BATCH), 512, 0, stream>>>(Vt, c2b, log_t, eT, log_s, eS, zb, P, 0);

  for (int k = 1; k <= 2; ++k) {
    k_gemm<256, 1><<<dim3(4, 8, BATCH), 256, 0, stream>>>(
        eS, NE_b, DD, c1b, C1_b, DD, (void*)Vt, NE_b, NN, 1.0f, nullptr);
    k_f2<0><<<dim3(16, BATCH), 256, 0, stream>>>(Vt, c2b, x, zb, log_s, log_t, eT,
                                                 nullptr, P, k);
    k_gemm<256, 1><<<dim3(4, 8, BATCH), 256, 0, stream>>>(
        eT, NE_b, DD, c1b, C1_b, DD, (void*)Vt, NE_b, NN, 1.0f, nullptr);
    k_f3<0><<<dim3(8, BATCH), 512, 0, stream>>>(Vt, c2b, log_t, eT, log_s, eS, zb, P, k);
  }

  // k = 3: only the T-half affects the output (tail-trim), fused with output partials
  k_gemm<256, 1><<<dim3(4, 8, BATCH), 256, 0, stream>>>(
      eS, NE_b, DD, c1b, C1_b, DD, (void*)Vt, NE_b, NN, 1.0f, nullptr);
  k_f2<1><<<dim3(16, BATCH), 256, 0, stream>>>(Vt, c2b, x, zb, log_s, log_t, eT,
                                               part, P, 3);
  k_out2<<<BATCH, 256, 0, stream>>>(part, out);
}

// Round 5
// 350.949 us; speedup vs baseline: 4.4219x; 1.0279x over previous
//
#include <hip/hip_runtime.h>
#include <math.h>

#define BATCH 32
#define NN 512
#define DD 256
#define NUMK 4

typedef __attribute__((ext_vector_type(8))) short bf16x8;
typedef __attribute__((ext_vector_type(4))) float f32x4;
typedef __attribute__((ext_vector_type(4))) unsigned short u16x4;

__device__ __forceinline__ float softplusf(float v) { return log1pf(expf(v)); }

__device__ __forceinline__ unsigned enc_key(float v) {
  unsigned u = __float_as_uint(v);
  return (u & 0x80000000u) ? ~u : (u | 0x80000000u);
}
__device__ __forceinline__ float dec_key(unsigned k) {
  return (k & 0x80000000u) ? __uint_as_float(k & 0x7fffffffu) : __uint_as_float(~k);
}
__device__ __forceinline__ unsigned short f2b(float f) {
  unsigned u = __float_as_uint(f);
  unsigned r = (u + 0x7fffu + ((u >> 16) & 1u)) >> 16;
  return (unsigned short)r;
}
__device__ __forceinline__ float b2f(unsigned short h) {
  return __uint_as_float(((unsigned)h) << 16);
}

#define GLDS(gp, lp)                                                   \
  __builtin_amdgcn_global_load_lds(                                    \
      (__attribute__((address_space(1))) void*)(void*)(gp),            \
      (__attribute__((address_space(3))) void*)(lp), 16, 0, 0)

// ---------- prep: xb = bf16(x) [n][d], xTb = bf16(x^T) [d][n]; zero max keys ----------
__global__ __launch_bounds__(256) void k_prep(const float* __restrict__ x,
                                              short* __restrict__ xb,
                                              short* __restrict__ xTb,
                                              unsigned* keys) {
  __shared__ float t[64][65];
  int b = blockIdx.z, n0 = blockIdx.y * 64, d0 = blockIdx.x * 64;
  if (blockIdx.x == 0 && blockIdx.y == 0 && blockIdx.z == 0 && threadIdx.x == 0) {
    keys[0] = 0u; keys[1] = 0u;
  }
  const float* X = x + (size_t)b * NN * DD;
  int col = threadIdx.x & 63, rr = threadIdx.x >> 6;
#pragma unroll
  for (int s = 0; s < 16; ++s) {
    int row = s * 4 + rr;
    float v = X[(size_t)(n0 + row) * DD + d0 + col];
    t[row][col] = v;
    xb[(size_t)b * NN * DD + (size_t)(n0 + row) * DD + d0 + col] = (short)f2b(v);
  }
  __syncthreads();
#pragma unroll
  for (int s = 0; s < 16; ++s) {
    int row = s * 4 + rr;  // d within tile
    xTb[(size_t)b * DD * NN + (size_t)(d0 + row) * NN + n0 + col] = (short)f2b(t[col][row]);
  }
}

// ---------- Gram / V GEMM: 64x64 tile, BK=64, swizzled LDS, batch-major grid ----------
// grid = (BATCH, mtiles, ntiles). C[m][c]=sum_k A[m][k]*B[c][k]; out[c*ldo+m].
template <int K, int OUTK>
__global__ __launch_bounds__(256) void k_gemm(
    const short* __restrict__ A, size_t sA, int lda,
    const short* __restrict__ Bp, size_t sB, int ldb,
    void* __restrict__ outp, size_t sO, int ldo,
    float scale, unsigned* maxslot) {
  __shared__ short As[64 * 64];
  __shared__ short Bs[64 * 64];
  const int b = blockIdx.x;
  const int m0 = blockIdx.y * 64, n0 = blockIdx.z * 64;
  const int tid = threadIdx.x, wave = tid >> 6, lane = tid & 63;
  const int ln = lane & 15, kg = lane >> 4;
  const int wr = (wave >> 1) * 32, wc = (wave & 1) * 32;
  const short* Ab = A + (size_t)b * sA;
  const short* Bb = Bp + (size_t)b * sB;
  const int srow = lane >> 3;
  const int sslot = lane & 7;

  f32x4 acc[2][2];
#pragma unroll
  for (int i = 0; i < 2; ++i)
#pragma unroll
    for (int j = 0; j < 2; ++j) acc[i][j] = (f32x4){0.f, 0.f, 0.f, 0.f};

  for (int k0 = 0; k0 < K; k0 += 64) {
    __syncthreads();
#pragma unroll
    for (int p = 0; p < 2; ++p) {
      int row = p * 32 + wave * 8 + srow;
      int sg = sslot ^ (row & 7);
      GLDS(Ab + (size_t)(m0 + row) * lda + k0 + sg * 8, &As[(p * 32 + wave * 8) * 64]);
      GLDS(Bb + (size_t)(n0 + row) * ldb + k0 + sg * 8, &Bs[(p * 32 + wave * 8) * 64]);
    }
    __syncthreads();
    bf16x8 af[2][2], bfr[2][2];
#pragma unroll
    for (int i = 0; i < 2; ++i)
#pragma unroll
      for (int kk = 0; kk < 2; ++kk) {
        int rowA = wr + i * 16 + ln;
        af[i][kk] = *(const bf16x8*)&As[rowA * 64 + (((kk * 4 + kg) ^ (rowA & 7)) * 8)];
        int rowB = wc + i * 16 + ln;
        bfr[i][kk] = *(const bf16x8*)&Bs[rowB * 64 + (((kk * 4 + kg) ^ (rowB & 7)) * 8)];
      }
#pragma unroll
    for (int kk = 0; kk < 2; ++kk)
#pragma unroll
      for (int i = 0; i < 2; ++i)
#pragma unroll
        for (int j = 0; j < 2; ++j)
          acc[i][j] = __builtin_amdgcn_mfma_f32_16x16x32_bf16(af[i][kk], bfr[j][kk],
                                                              acc[i][j], 0, 0, 0);
  }

  unsigned short* ot = (unsigned short*)outp + (size_t)b * sO;
  float tmax = -1e30f;
#pragma unroll
  for (int i = 0; i < 2; ++i) {
    int r = m0 + wr + i * 16 + kg * 4;
#pragma unroll
    for (int j = 0; j < 2; ++j) {
      int c = n0 + wc + j * 16 + ln;
      u16x4 pk;
#pragma unroll
      for (int q = 0; q < 4; ++q) {
        float v = acc[i][j][q] * scale;
        if (OUTK == 0) tmax = fmaxf(tmax, v);
        pk[q] = f2b(v);
      }
      *(u16x4*)&ot[(size_t)c * ldo + r] = pk;
    }
  }
  if (OUTK == 0) {
#pragma unroll
    for (int o = 32; o > 0; o >>= 1) tmax = fmaxf(tmax, __shfl_xor(tmax, o));
    __syncthreads();
    float* smf = (float*)As;
    if (lane == 0) smf[wave] = tmax;
    __syncthreads();
    if (tid == 0)
      atomicMax(maxslot, enc_key(fmaxf(fmaxf(smf[0], smf[1]), fmaxf(smf[2], smf[3]))));
  }
}

// ---------- misc: row sums of c2/c1 + scalar params, one launch ----------
__global__ __launch_bounds__(256) void k_misc(const short* __restrict__ c2b,
                                              const short* __restrict__ c1b,
                                              float* __restrict__ r2,
                                              float* __restrict__ s1,
                                              const float* a0p, const float* a1p,
                                              const float* a2p, const float* a3p,
                                              const float* rhop, float* P,
                                              const unsigned* keys) {
  int bid = blockIdx.x;
  int lane = threadIdx.x & 63;
  if (bid < 4096) {
    int row = bid * 4 + (threadIdx.x >> 6);
    bf16x8 v = *(const bf16x8*)(c2b + (size_t)row * 512 + lane * 8);
    float s = 0.f;
#pragma unroll
    for (int q = 0; q < 8; ++q) s += b2f((unsigned short)v[q]);
#pragma unroll
    for (int o = 32; o > 0; o >>= 1) s += __shfl_xor(s, o);
    if (lane == 0) r2[row] = s;
  } else if (bid < 6144) {
    int row = (bid - 4096) * 4 + (threadIdx.x >> 6);
    u16x4 v = *(const u16x4*)(c1b + (size_t)row * 256 + lane * 4);
    float s = 0.f;
#pragma unroll
    for (int q = 0; q < 4; ++q) s += b2f(v[q]);
#pragma unroll
    for (int o = 32; o > 0; o >>= 1) s += __shfl_xor(s, o);
    if (lane == 0) s1[row] = s;
  } else if (threadIdx.x == 0) {
    float M1 = dec_key(keys[0]);
    float M2 = dec_key(keys[1]);
    float lq0 = logf(1.0f / NN + 1e-8f);
    float lp0 = logf(1.0f / DD + 1e-8f);
    float mu = lq0, eta = lp0, z1 = 0.f, z2 = 0.f;
    for (int k = 0; k < NUMK; ++k) {
      float a0 = softplusf(a0p[k]), a1 = softplusf(a1p[k]);
      float a2 = softplusf(a2p[k]), a3 = softplusf(a3p[k]);
      float rho = softplusf(rhop[k]);
      P[0 + k] = a0;
      P[4 + k] = a1 / (M1 * M2);
      P[8 + k] = rho;
      P[12 + k] = mu;
      P[16 + k] = eta;
      float t1 = mu;
      mu = (a2 * lq0 + rho * t1 - z1) / (a2 + rho);
      z1 += rho * (expf(mu) - expf(t1));
      float s1v = eta;
      eta = (a3 * lp0 + rho * s1v - z2) / (a3 + rho);
      z2 += rho * (expf(eta) - expf(s1v));
    }
  }
}

// ---------- iter-0 T-update via rank-1 gw ----------
__global__ __launch_bounds__(256) void k_trow0(const float* __restrict__ x,
                                               const float* __restrict__ r2,
                                               const float* __restrict__ s1,
                                               float* __restrict__ log_t,
                                               short* __restrict__ eT,
                                               const float* __restrict__ P) {
  size_t row = blockIdx.x;  // b*N + n
  int b = (int)(row >> 9);
  const float c0 = logf(1.0f / NN + 1e-8f) + logf(1.0f / DD + 1e-8f);
  float g = P[4] * expf(c0) * r2[row];
  float inv = 1.0f / (P[8] + P[0]);
  float y = (x[row * DD + threadIdx.x] + g * s1[(size_t)b * DD + threadIdx.x]) * inv;
  float m = y;
#pragma unroll
  for (int o = 32; o > 0; o >>= 1) m = fmaxf(m, __shfl_xor(m, o));
  __shared__ float sm[4], ss[4];
  int wv = threadIdx.x >> 6;
  if ((threadIdx.x & 63) == 0) sm[wv] = m;
  __syncthreads();
  m = fmaxf(fmaxf(sm[0], sm[1]), fmaxf(sm[2], sm[3]));
  float sum = expf(y - m);
#pragma unroll
  for (int o = 32; o > 0; o >>= 1) sum += __shfl_xor(sum, o);
  if ((threadIdx.x & 63) == 0) ss[wv] = sum;
  __syncthreads();
  float lse = m + logf(ss[0] + ss[1] + ss[2] + ss[3]);
  float lt = P[12] + y - lse;
  log_t[row * DD + threadIdx.x] = lt;
  eT[row * DD + threadIdx.x] = (short)f2b(expf(lt));
}

// ---------- F2: fused y-GEMM + T-softmax (axis=d), barrier-free reg-pipelined GEMM ----------
// grid (BATCH, 16). Block: all 256 d x 32 n; 4 waves, wave owns d in [w*64, w*64+64).
#define LDF2(AF, BF, K0)                                                          \
  {                                                                               \
    _Pragma("unroll") for (int i_ = 0; i_ < 4; ++i_)                              \
        AF[i_] = *(const bf16x8*)&Av[(size_t)(wave * 64 + i_ * 16 + ln) * NN +    \
                                     (K0) + kg * 8];                              \
    _Pragma("unroll") for (int j_ = 0; j_ < 2; ++j_)                              \
        BF[j_] = *(const bf16x8*)&Bv[(size_t)(n0 + j_ * 16 + ln) * NN +           \
                                     (K0) + kg * 8];                              \
  }
#define MMF2(AF, BF)                                                              \
  _Pragma("unroll") for (int i_ = 0; i_ < 4; ++i_)                                \
      _Pragma("unroll") for (int j_ = 0; j_ < 2; ++j_)                            \
          acc[i_][j_] = __builtin_amdgcn_mfma_f32_16x16x32_bf16(AF[i_], BF[j_],   \
                                                                acc[i_][j_], 0, 0, 0);

template <int LAST>
__global__ __launch_bounds__(256) void k_f2(
    const short* __restrict__ Vt, const short* __restrict__ c2b,
    const float* __restrict__ x, const float* __restrict__ z,
    const float* __restrict__ log_s, float* __restrict__ log_t,
    short* __restrict__ eT, float* __restrict__ part,
    const float* __restrict__ P, int kiter) {
  __shared__ float red[128];
  const int b = blockIdx.x;
  const int n0 = blockIdx.y * 32;
  const int tid = threadIdx.x, wave = tid >> 6, lane = tid & 63;
  const int ln = lane & 15, kg = lane >> 4;
  const short* Av = Vt + (size_t)b * ((size_t)NN * DD);
  const short* Bv = c2b + (size_t)b * ((size_t)NN * NN);
  const size_t base = (size_t)b * ((size_t)NN * DD);

  f32x4 acc[4][2];
#pragma unroll
  for (int i = 0; i < 4; ++i)
#pragma unroll
    for (int j = 0; j < 2; ++j) acc[i][j] = (f32x4){0.f, 0.f, 0.f, 0.f};

  {
    bf16x8 a0[4], b0[2], a1[4], b1[2];
    LDF2(a0, b0, 0);
#pragma unroll
    for (int k0 = 0; k0 < NN; k0 += 64) {
      LDF2(a1, b1, k0 + 32);
      MMF2(a0, b0);
      if (k0 + 64 < NN) LDF2(a0, b0, k0 + 64);
      MMF2(a1, b1);
    }
  }

  const float a0p_ = P[kiter], a1e = P[4 + kiter], rho = P[8 + kiter], mu = P[12 + kiter];
  const float inv = 1.0f / (rho + a0p_);
#pragma unroll
  for (int i = 0; i < 4; ++i) {
    int r = wave * 64 + i * 16 + kg * 4;
#pragma unroll
    for (int j = 0; j < 2; ++j) {
      int c = n0 + j * 16 + ln;
      size_t idx = base + (size_t)c * DD + r;
      f32x4 xv = *(const f32x4*)&x[idx];
      f32x4 zv = *(const f32x4*)&z[idx];
      f32x4 lv = *(const f32x4*)&log_s[idx];
#pragma unroll
      for (int q = 0; q < 4; ++q)
        acc[i][j][q] = (xv[q] + a1e * acc[i][j][q] + zv[q] + rho * lv[q]) * inv;
    }
  }
  // softmax over d (per c): in-lane (i,q) -> kg (shfl) -> wave (LDS)
  float pm[2], mc[2], ps[2], lse[2];
#pragma unroll
  for (int j = 0; j < 2; ++j) {
    float m = -1e30f;
#pragma unroll
    for (int i = 0; i < 4; ++i)
#pragma unroll
      for (int q = 0; q < 4; ++q) m = fmaxf(m, acc[i][j][q]);
    m = fmaxf(m, __shfl_xor(m, 16));
    m = fmaxf(m, __shfl_xor(m, 32));
    pm[j] = m;
  }
  if (lane < 16) {
    red[wave * 32 + lane] = pm[0];
    red[wave * 32 + 16 + lane] = pm[1];
  }
  __syncthreads();
#pragma unroll
  for (int j = 0; j < 2; ++j)
    mc[j] = fmaxf(fmaxf(red[j * 16 + ln], red[32 + j * 16 + ln]),
                  fmaxf(red[64 + j * 16 + ln], red[96 + j * 16 + ln]));
  __syncthreads();
#pragma unroll
  for (int j = 0; j < 2; ++j) {
    float s = 0.f;
#pragma unroll
    for (int i = 0; i < 4; ++i)
#pragma unroll
      for (int q = 0; q < 4; ++q) s += expf(acc[i][j][q] - mc[j]);
    s += __shfl_xor(s, 16);
    s += __shfl_xor(s, 32);
    ps[j] = s;
  }
  if (lane < 16) {
    red[wave * 32 + lane] = ps[0];
    red[wave * 32 + 16 + lane] = ps[1];
  }
  __syncthreads();
#pragma unroll
  for (int j = 0; j < 2; ++j)
    lse[j] = mc[j] + logf(red[j * 16 + ln] + red[32 + j * 16 + ln] +
                          red[64 + j * 16 + ln] + red[96 + j * 16 + ln]);

  if (LAST == 0) {
#pragma unroll
    for (int i = 0; i < 4; ++i) {
      int r = wave * 64 + i * 16 + kg * 4;
#pragma unroll
      for (int j = 0; j < 2; ++j) {
        int c = n0 + j * 16 + ln;
        size_t idx = base + (size_t)c * DD + r;
        f32x4 lt;
        u16x4 et;
#pragma unroll
        for (int q = 0; q < 4; ++q) {
          float v = mu + acc[i][j][q] - lse[j];
          lt[q] = v;
          et[q] = f2b(expf(v));
        }
        *(f32x4*)&log_t[idx] = lt;
        *(u16x4*)&eT[idx] = et;
      }
    }
  } else {
    const size_t pbase = ((size_t)b * 16 + blockIdx.y) * DD;
#pragma unroll
    for (int i = 0; i < 4; ++i) {
      int r = wave * 64 + i * 16 + kg * 4;
      float p0 = 0.f, p1 = 0.f, p2 = 0.f, p3 = 0.f;
#pragma unroll
      for (int j = 0; j < 2; ++j) {
        int c = n0 + j * 16 + ln;
        size_t idx = base + (size_t)c * DD + r;
        f32x4 xv = *(const f32x4*)&x[idx];
        p0 += expf(mu + acc[i][j][0] - lse[j]) * xv[0];
        p1 += expf(mu + acc[i][j][1] - lse[j]) * xv[1];
        p2 += expf(mu + acc[i][j][2] - lse[j]) * xv[2];
        p3 += expf(mu + acc[i][j][3] - lse[j]) * xv[3];
      }
#pragma unroll
      for (int o = 1; o < 16; o <<= 1) {
        p0 += __shfl_xor(p0, o);
        p1 += __shfl_xor(p1, o);
        p2 += __shfl_xor(p2, o);
        p3 += __shfl_xor(p3, o);
      }
      if (ln == 0) {
        part[pbase + r + 0] = p0;
        part[pbase + r + 1] = p1;
        part[pbase + r + 2] = p2;
        part[pbase + r + 3] = p3;
      }
    }
  }
}

// ---------- F3: fused y2-GEMM + S-softmax (axis=n) + dual z-update, barrier-free ----------
// grid (BATCH, 8). Block: 32 d x all 512 n; 8 waves, wave owns n in [w*64, w*64+64).
#define LDF3(AF, BF, K0)                                                          \
  {                                                                               \
    _Pragma("unroll") for (int i_ = 0; i_ < 2; ++i_)                              \
        AF[i_] = *(const bf16x8*)&Av[(size_t)(m0 + i_ * 16 + ln) * NN +           \
                                     (K0) + kg * 8];                              \
    _Pragma("unroll") for (int j_ = 0; j_ < 4; ++j_)                              \
        BF[j_] = *(const bf16x8*)&Bv[(size_t)(wave * 64 + j_ * 16 + ln) * NN +    \
                                     (K0) + kg * 8];                              \
  }
#define MMF3(AF, BF)                                                              \
  _Pragma("unroll") for (int i_ = 0; i_ < 2; ++i_)                                \
      _Pragma("unroll") for (int j_ = 0; j_ < 4; ++j_)                            \
          acc[i_][j_] = __builtin_amdgcn_mfma_f32_16x16x32_bf16(AF[i_], BF[j_],   \
                                                                acc[i_][j_], 0, 0, 0);

template <int ZFIRST>
__global__ __launch_bounds__(512) void k_f3(
    const short* __restrict__ Vt, const short* __restrict__ c2b,
    const float* __restrict__ log_t, const short* __restrict__ eT,
    float* __restrict__ log_s, short* __restrict__ eS, float* __restrict__ z,
    const float* __restrict__ P, int kiter) {
  __shared__ float red[320];
  const int b = blockIdx.x;
  const int m0 = blockIdx.y * 32;
  const int tid = threadIdx.x, wave = tid >> 6, lane = tid & 63;
  const int ln = lane & 15, kg = lane >> 4;
  const short* Av = Vt + (size_t)b * ((size_t)NN * DD);
  const short* Bv = c2b + (size_t)b * ((size_t)NN * NN);
  const size_t base = (size_t)b * ((size_t)NN * DD);

  f32x4 acc[2][4];
#pragma unroll
  for (int i = 0; i < 2; ++i)
#pragma unroll
    for (int j = 0; j < 4; ++j) acc[i][j] = (f32x4){0.f, 0.f, 0.f, 0.f};

  {
    bf16x8 a0[2], b0[4], a1[2], b1[4];
    LDF3(a0, b0, 0);
#pragma unroll
    for (int k0 = 0; k0 < NN; k0 += 64) {
      LDF3(a1, b1, k0 + 32);
      MMF3(a0, b0);
      if (k0 + 64 < NN) LDF3(a0, b0, k0 + 64);
      MMF3(a1, b1);
    }
  }

  const float a1e = P[4 + kiter], rho = P[8 + kiter], eta = P[16 + kiter];
  const float invr = 1.0f / rho;
  f32x4 zreg[2][4];
  // epilogue: y2 into acc (z kept in registers for the dual update)
#pragma unroll
  for (int i = 0; i < 2; ++i) {
    int r = m0 + i * 16 + kg * 4;
#pragma unroll
    for (int j = 0; j < 4; ++j) {
      int c = wave * 64 + j * 16 + ln;
      size_t idx = base + (size_t)c * DD + r;
      f32x4 lv = *(const f32x4*)&log_t[idx];
      if (ZFIRST) zreg[i][j] = (f32x4){0.f, 0.f, 0.f, 0.f};
      else zreg[i][j] = *(const f32x4*)&z[idx];
#pragma unroll
      for (int q = 0; q < 4; ++q)
        acc[i][j][q] = (a1e * acc[i][j][q] - zreg[i][j][q] + rho * lv[q]) * invr;
    }
  }
  // softmax over n (per d): in-lane j -> ln (shfl) -> wave (LDS)
  float pm[2][4];
#pragma unroll
  for (int i = 0; i < 2; ++i)
#pragma unroll
    for (int q = 0; q < 4; ++q) {
      float m = fmaxf(fmaxf(acc[i][0][q], acc[i][1][q]), fmaxf(acc[i][2][q], acc[i][3][q]));
#pragma unroll
      for (int o = 1; o < 16; o <<= 1) m = fmaxf(m, __shfl_xor(m, o));
      pm[i][q] = m;
    }
  if (ln == 0) {
#pragma unroll
    for (int i = 0; i < 2; ++i)
#pragma unroll
      for (int q = 0; q < 4; ++q) red[wave * 32 + i * 16 + kg * 4 + q] = pm[i][q];
  }
  __syncthreads();
  if (tid < 32) {
    float M = -1e30f;
#pragma unroll
    for (int w = 0; w < 8; ++w) M = fmaxf(M, red[w * 32 + tid]);
    red[256 + tid] = M;
  }
  __syncthreads();
  float mc[2][4], ps[2][4];
#pragma unroll
  for (int i = 0; i < 2; ++i)
#pragma unroll
    for (int q = 0; q < 4; ++q) {
      mc[i][q] = red[256 + i * 16 + kg * 4 + q];
      float s = expf(acc[i][0][q] - mc[i][q]) + expf(acc[i][1][q] - mc[i][q]) +
                expf(acc[i][2][q] - mc[i][q]) + expf(acc[i][3][q] - mc[i][q]);
#pragma unroll
      for (int o = 1; o < 16; o <<= 1) s += __shfl_xor(s, o);
      ps[i][q] = s;
    }
  __syncthreads();
  if (ln == 0) {
#pragma unroll
    for (int i = 0; i < 2; ++i)
#pragma unroll
      for (int q = 0; q < 4; ++q) red[wave * 32 + i * 16 + kg * 4 + q] = ps[i][q];
  }
  __syncthreads();
  if (tid < 32) {
    float S = 0.f;
#pragma unroll
    for (int w = 0; w < 8; ++w) S += red[w * 32 + tid];
    red[288 + tid] = red[256 + tid] + logf(S);
  }
  __syncthreads();
  float lsev[2][4];
#pragma unroll
  for (int i = 0; i < 2; ++i)
#pragma unroll
    for (int q = 0; q < 4; ++q) lsev[i][q] = red[288 + i * 16 + kg * 4 + q];

  // final: log_s, eS, z-update
#pragma unroll
  for (int i = 0; i < 2; ++i) {
    int r = m0 + i * 16 + kg * 4;
#pragma unroll
    for (int j = 0; j < 4; ++j) {
      int c = wave * 64 + j * 16 + ln;
      size_t idx = base + (size_t)c * DD + r;
      f32x4 ls, esf;
      u16x4 ev;
#pragma unroll
      for (int q = 0; q < 4; ++q) {
        float v = eta + acc[i][j][q] - lsev[i][q];
        ls[q] = v;
        float e = expf(v);
        esf[q] = e;
        ev[q] = f2b(e);
      }
      *(f32x4*)&log_s[idx] = ls;
      *(u16x4*)&eS[idx] = ev;
      u16x4 et = *(const u16x4*)&eT[idx];
      f32x4 zo;
#pragma unroll
      for (int q = 0; q < 4; ++q) zo[q] = zreg[i][j][q] + rho * (b2f(et[q]) - esf[q]);
      *(f32x4*)&z[idx] = zo;
    }
  }
}

// ---------- final reduce: out[b][d] = D * sum over 16 partial chunks ----------
__global__ __launch_bounds__(256) void k_out2(const float* __restrict__ part,
                                              float* __restrict__ out) {
  int b = blockIdx.x, d = threadIdx.x;
  float acc = 0.0f;
#pragma unroll
  for (int c = 0; c < 16; ++c) acc += part[((size_t)b * 16 + c) * DD + d];
  out[(size_t)b * DD + d] = (float)DD * acc;
}

// ---------- launch ----------
extern "C" void kernel_launch(void* const* d_in, const int* in_sizes, int n_in,
                              void* d_out, int out_size, void* d_ws, size_t ws_size,
                              hipStream_t stream) {
  const float* x = (const float*)d_in[0];
  const float* a0p = (const float*)d_in[1];
  const float* a1p = (const float*)d_in[2];
  const float* a2p = (const float*)d_in[3];
  const float* a3p = (const float*)d_in[4];
  const float* rhop = (const float*)d_in[5];
  float* out = (float*)d_out;

  const size_t NE = (size_t)BATCH * NN * DD;
  const size_t NE_b = (size_t)NN * DD;
  const size_t C2_b = (size_t)NN * NN;
  const size_t C1_b = (size_t)DD * DD;

  float* fws = (float*)d_ws;
  float* log_t = fws;              // NE
  float* log_s = fws + NE;         // NE
  float* zb = fws + 2 * NE;        // NE
  float* part = fws + 3 * NE;      // B*16*DD
  float* r2 = part + 131072;       // B*N
  float* s1 = r2 + BATCH * NN;     // B*D
  float* P = s1 + BATCH * DD;      // 24
  unsigned* keys = (unsigned*)(P + 24);
  short* sws = (short*)(keys + 8);
  short* xb = sws;                 // NE (aliased: eS)
  short* xTb = sws + NE;           // NE (aliased: eT)
  short* eS = xb;
  short* eT = xTb;
  short* Vt = sws + 2 * NE;        // NE
  short* c1b = sws + 3 * NE;       // B*D*D
  short* c2b = c1b + (size_t)BATCH * C1_b;  // B*N*N

  k_prep<<<dim3(4, 8, BATCH), 256, 0, stream>>>(x, xb, xTb, keys);
  k_gemm<256, 0><<<dim3(BATCH, 8, 8), 256, 0, stream>>>(
      xb, NE_b, DD, xb, NE_b, DD, (void*)c2b, C2_b, NN, 1.0f / DD, keys + 1);
  k_gemm<512, 0><<<dim3(BATCH, 4, 4), 256, 0, stream>>>(
      xTb, NE_b, NN, xTb, NE_b, NN, (void*)c1b, C1_b, DD, 1.0f / NN, keys + 0);
  k_misc<<<6145, 256, 0, stream>>>(c2b, c1b, r2, s1, a0p, a1p, a2p, a3p, rhop, P, keys);

  // k = 0: rank-1 T-update, then S-half
  k_trow0<<<BATCH * NN, 256, 0, stream>>>(x, r2, s1, log_t, eT, P);
  k_gemm<256, 1><<<dim3(BATCH, 8, 4), 256, 0, stream>>>(
      eT, NE_b, DD, c1b, C1_b, DD, (void*)Vt, NE_b, NN, 1.0f, nullptr);
  k_f3<1><<<dim3(BATCH, 8), 512, 0, stream>>>(Vt, c2b, log_t, eT, log_s, eS, zb, P, 0);

  for (int k = 1; k <= 2; ++k) {
    k_gemm<256, 1><<<dim3(BATCH, 8, 4), 256, 0, stream>>>(
        eS, NE_b, DD, c1b, C1_b, DD, (void*)Vt, NE_b, NN, 1.0f, nullptr);
    k_f2<0><<<dim3(BATCH, 16), 256, 0, stream>>>(Vt, c2b, x, zb, log_s, log_t, eT,
                                                 nullptr, P, k);
    k_gemm<256, 1><<<dim3(BATCH, 8, 4), 256, 0, stream>>>(
        eT, NE_b, DD, c1b, C1_b, DD, (void*)Vt, NE_b, NN, 1.0f, nullptr);
    k_f3<0><<<dim3(BATCH, 8), 512, 0, stream>>>(Vt, c2b, log_t, eT, log_s, eS, zb, P, k);
  }

  // k = 3: only the T-half affects the output (tail-trim), fused with output partials
  k_gemm<256, 1><<<dim3(BATCH, 8, 4), 256, 0, stream>>>(
      eS, NE_b, DD, c1b, C1_b, DD, (void*)Vt, NE_b, NN, 1.0f, nullptr);
  k_f2<1><<<dim3(BATCH, 16), 256, 0, stream>>>(Vt, c2b, x, zb, log_s, log_t, eT,
                                               part, P, 3);
  k_out2<<<BATCH, 256, 0, stream>>>(part, out);
}